// Round 18
// baseline (578.406 us; speedup 1.0000x reference)
//
#include <hip/hip_runtime.h>
#include <math.h>

// Problem constants (from setup_inputs)
#define BATCH 256
#define NQ 30
#define NK 100
#define HID 512
#define WORD 300
#define KIN 900          // WORD*3
#define KP 928           // KIN padded to multiple of 32
#define NANS 32000
#define NOUT 300
#define NOUTP 384        // NOUT padded (MFMA K for sim)
#define NTG 12           // NOUTP/32
#define NLAYERS 3
#define MQT (BATCH * NQ)   // 7680 gather rows (packed 30/b)
#define MQ32 (BATCH * 32)  // 8192 q-state rows (32/b)
#define MKT (BATCH * NK)   // 25600
#define SCALE 0.044194173824159216f  // 1/sqrt(512)
#define CLDST 136          // C-tile LDS row stride (u16)
#define SST 36             // S LDS row stride (floats)

typedef __attribute__((ext_vector_type(8))) short bf16x8;
typedef __attribute__((ext_vector_type(4))) float f32x4;
typedef unsigned short ushort_t;

__device__ __forceinline__ unsigned short f2bf(float f) {
  unsigned int u = __float_as_uint(f);
  u = (u + 0x7FFF + ((u >> 16) & 1)) >> 16;  // RNE
  return (unsigned short)u;
}
__device__ __forceinline__ float bf2f(unsigned short s) {
  return __uint_as_float(((unsigned int)s) << 16);
}

typedef const __attribute__((address_space(1))) unsigned int* gas_u32;
typedef __attribute__((address_space(3))) unsigned int* las_u32;
__device__ __forceinline__ void gld_lds16(const void* g, void* l) {
  __builtin_amdgcn_global_load_lds((gas_u32)g, (las_u32)l, 16, 0, 0);
}

// bijective XCD swizzle (m204)
__device__ __forceinline__ int xcd_swz_linear() {
  const int nwg = gridDim.x * gridDim.y;
  const int orig = blockIdx.y * gridDim.x + blockIdx.x;
  const int q = nwg >> 3, r = nwg & 7;
  const int xcd = orig & 7, idx = orig >> 3;
  return (xcd < r ? xcd * (q + 1) : r * (q + 1) + (xcd - r) * q) + idx;
}

// ---------------- reduction helpers ----------------
__device__ __forceinline__ float waveReduceSum(float v) {
#pragma unroll
  for (int o = 32; o > 0; o >>= 1) v += __shfl_xor(v, o);
  return v;
}
__device__ __forceinline__ float waveReduceMax(float v) {
#pragma unroll
  for (int o = 32; o > 0; o >>= 1) v = fmaxf(v, __shfl_xor(v, o));
  return v;
}
__device__ float blockReduceSum512(float v) {
  __shared__ float sm[8];
  int lane = threadIdx.x & 63, w = threadIdx.x >> 6;
  v = waveReduceSum(v);
  if (lane == 0) sm[w] = v;
  __syncthreads();
  float r = 0.f;
#pragma unroll
  for (int i = 0; i < 8; ++i) r += sm[i];
  __syncthreads();
  return r;
}

// ---------------- bf16 MFMA GEMM: 2-phase dbuf, LDS epilogue, RESID/TRANS --
// RESID: add bf16 residual R (same layout as Cb) before rounding.
// TRANS: also emit transposed bf16 output T[b2][col][r] (pbt r-capacity),
//        b2 = (row0+ml)/pb (+ z), from the LDS-staged tile.
// mv: valid rows per tile for the linear bf16 store (guards packed overrun).
template <int SWZB, int BIAS, int OUTF32, int OUTBF16, int ZC0, int RELU,
          int RESID, int TRANS>
__global__ __launch_bounds__(256) void mfma_gemm2(
    const ushort_t* __restrict__ A1, const ushort_t* __restrict__ Bt1,
    const float* __restrict__ bias1, float* __restrict__ C1,
    ushort_t* __restrict__ Cb1, const ushort_t* __restrict__ R1,
    ushort_t* __restrict__ TB1, int pb1, int pbt1, size_t zsT1, int M1b,
    const ushort_t* __restrict__ A2, const ushort_t* __restrict__ Bt2,
    const float* __restrict__ bias2, float* __restrict__ C2,
    ushort_t* __restrict__ Cb2, const ushort_t* __restrict__ R2,
    ushort_t* __restrict__ TB2, int pb2, int pbt2, size_t zsT2,
    size_t zsA, size_t zsB, size_t zsC,
    int N, int K, int nbias, int mv) {
  __shared__ __align__(16) ushort_t smem[128 * CLDST];
  const int wg = xcd_swz_linear();
  const int bx = wg % gridDim.x, by = wg / gridDim.x;
  const int z = blockIdx.z;
  const bool sel = (by >= M1b);
  const ushort_t* A = (sel ? A2 : A1) + z * zsA;
  const ushort_t* Bt = (sel ? Bt2 : Bt1) + z * zsB;
  const float* bias = sel ? bias2 : bias1;
  float* C = (sel ? C2 : C1);
  ushort_t* Cb = (sel ? Cb2 : Cb1);
  const ushort_t* R = (sel ? R2 : R1);
  ushort_t* TB = (sel ? TB2 : TB1);
  const int pb = sel ? pb2 : pb1;
  const int pbt = sel ? pbt2 : pbt1;
  const size_t zsT = sel ? zsT2 : zsT1;
  if (C) C += z * zsC;
  if (Cb) Cb += z * zsC;
  if (RESID && R) R += z * zsC;
  const int row0 = (sel ? (by - M1b) : by) * 128;
  const int col0 = bx * 128;

  const int tid = threadIdx.x;
  const int lane = tid & 63, w = tid >> 6;
  const int wr = w >> 1, wc = w & 1;
  const int s_r = lane & 15, s_kq = lane >> 4;
  const int nt = K / 32;

  const size_t a_src0 = (size_t)(row0 + (w * 2 + 0) * 16 + s_r) * K + s_kq * 8;
  const size_t a_src1 = (size_t)(row0 + (w * 2 + 1) * 16 + s_r) * K + s_kq * 8;
  const size_t b_lin0 = (size_t)(col0 + (w * 2 + 0) * 16 + s_r) * K + s_kq * 8;
  const size_t b_lin1 = (size_t)(col0 + (w * 2 + 1) * 16 + s_r) * K + s_kq * 8;
  const size_t b_swz0 = ((size_t)(col0 >> 7) * nt) * 4096 + (w * 2 + 0) * 512 + lane * 8;
  const size_t b_swz1 = b_swz0 + 512;

  auto stageAB = [&](int t, int bsel) {
    const int k0 = t * 32;
    ushort_t* Ab = smem + bsel * 4096;
    ushort_t* Bb = smem + 8192 + bsel * 4096;
    gld_lds16(A + a_src0 + k0, Ab + (w * 2 + 0) * 512);
    gld_lds16(A + a_src1 + k0, Ab + (w * 2 + 1) * 512);
    if (SWZB) {
      gld_lds16(Bt + b_swz0 + (size_t)t * 4096, Bb + (w * 2 + 0) * 512);
      gld_lds16(Bt + b_swz1 + (size_t)t * 4096, Bb + (w * 2 + 1) * 512);
    } else {
      gld_lds16(Bt + b_lin0 + k0, Bb + (w * 2 + 0) * 512);
      gld_lds16(Bt + b_lin1 + k0, Bb + (w * 2 + 1) * 512);
    }
  };

  f32x4 acc[4][4];
#pragma unroll
  for (int i = 0; i < 4; ++i)
#pragma unroll
    for (int j = 0; j < 4; ++j) acc[i][j] = (f32x4){0.f, 0.f, 0.f, 0.f};

  stageAB(0, 0);
  __syncthreads();
  for (int t = 0; t < nt; ++t) {
    const int cur = t & 1;
    if (t + 1 < nt) stageAB(t + 1, cur ^ 1);
    const ushort_t* Ab = smem + cur * 4096;
    const ushort_t* Bb = smem + 8192 + cur * 4096;
    bf16x8 af[4], bfr[4];
#pragma unroll
    for (int mi = 0; mi < 4; ++mi)
      af[mi] = *(const bf16x8*)(Ab + (wr * 4 + mi) * 512 + lane * 8);
#pragma unroll
    for (int nj = 0; nj < 4; ++nj)
      bfr[nj] = *(const bf16x8*)(Bb + (wc * 4 + nj) * 512 + lane * 8);
#pragma unroll
    for (int mi = 0; mi < 4; ++mi)
#pragma unroll
      for (int nj = 0; nj < 4; ++nj)
        acc[mi][nj] = __builtin_amdgcn_mfma_f32_16x16x32_bf16(
            af[mi], bfr[nj], acc[mi][nj], 0, 0, 0);
    __syncthreads();
  }

  if (OUTBF16) {
    // stage bf16 tile (bias/relu/zc0/residual applied) into LDS
#pragma unroll
    for (int nj = 0; nj < 4; ++nj) {
      const int nl = wc * 64 + nj * 16 + (lane & 15);
      const int n = col0 + nl;
      const float bb = BIAS ? ((n < nbias) ? bias[n] : 0.f) : 0.f;
#pragma unroll
      for (int mi = 0; mi < 4; ++mi) {
        f32x4 v = acc[mi][nj];
#pragma unroll
        for (int r = 0; r < 4; ++r) {
          const int ml = wr * 64 + mi * 16 + (lane >> 4) * 4 + r;
          float val = v[r] + bb;
          if (RELU) val = fmaxf(val, 0.f);
          if (ZC0 && n == 0) val = 0.f;
          if (RESID) val += bf2f(R[(size_t)(row0 + ml) * N + n]);
          smem[ml * CLDST + nl] = f2bf(val);
        }
      }
    }
    __syncthreads();
    // linear coalesced store (guarded by mv)
#pragma unroll
    for (int j = 0; j < 8; ++j) {
      const int e = j * 2048 + tid * 8;
      const int ml = e >> 7, nl = e & 127;
      if (ml < mv) {
        uint4 v = *(const uint4*)(smem + ml * CLDST + nl);
        *(uint4*)(Cb + (size_t)(row0 + ml) * N + col0 + nl) = v;
      }
    }
    if (TRANS) {
      const int colL = tid & 127;
#pragma unroll
      for (int t2 = 0; t2 < 8; ++t2) {
        const int grp = (tid >> 7) + t2 * 2;
        const int mlb = grp * 8;
        const int grow = row0 + mlb;
        const int b2 = grow / pb;
        const int r = grow - b2 * pb;
        if (r >= pbt) continue;
        union { ushort_t u[8]; uint4 v; ushort4 h[2]; } pk;
#pragma unroll
        for (int j = 0; j < 8; ++j) pk.u[j] = smem[(mlb + j) * CLDST + colL];
        ushort_t* tb = TB + (size_t)(z + b2) * zsT + (size_t)(col0 + colL) * pbt;
        if (r + 8 <= pb) {
          if ((r & 7) == 0) {
            *(uint4*)(tb + r) = pk.v;
          } else {
            *(ushort4*)(tb + r) = pk.h[0];
            *(ushort4*)(tb + r + 4) = pk.h[1];
          }
        } else {
          // crossing (r == pb-4 by construction): split 4 + 4
          *(ushort4*)(tb + r) = pk.h[0];
          ushort_t* tb2 = TB + (size_t)(z + b2 + 1) * zsT + (size_t)(col0 + colL) * pbt;
          *(ushort4*)tb2 = pk.h[1];
        }
      }
    }
  }
  if (OUTF32) {
#pragma unroll
    for (int nj = 0; nj < 4; ++nj) {
      const int n = col0 + wc * 64 + nj * 16 + (lane & 15);
      const float bb = BIAS ? ((n < nbias) ? bias[n] : 0.f) : 0.f;
#pragma unroll
      for (int mi = 0; mi < 4; ++mi) {
        f32x4 v = acc[mi][nj];
#pragma unroll
        for (int r = 0; r < 4; ++r) {
          const int m = row0 + wr * 64 + mi * 16 + (lane >> 4) * 4 + r;
          float val = v[r] + bb;
          if (RELU) val = fmaxf(val, 0.f);
          if (ZC0 && n == 0) val = 0.f;
          C[(size_t)m * N + n] = val;
        }
      }
    }
  }
}

// ---------------- S + dual softmax -> P operands (A-fragment layouts) ------
__global__ __launch_bounds__(512) void s_softmax_k(
    const ushort_t* __restrict__ Kc, const ushort_t* __restrict__ Qps,
    ushort_t* __restrict__ Pk, ushort_t* __restrict__ Pq) {
  const int b = blockIdx.x;
  __shared__ __align__(16) float S_lds[112 * SST];
  const int tid = threadIdx.x;
  const int w = tid >> 6, lane = tid & 63;
  if (w < 7) {
    const int r = lane & 15, kq = lane >> 4;
    const ushort_t* ktb = Kc + (size_t)b * NK * HID;
    const ushort_t* qpb = Qps + (size_t)b * 32 * HID;
    const int rowA = w * 16 + r;
    const int rowA_c = (rowA < NK) ? rowA : (NK - 1);
    const int qr1 = (16 + r) < NQ ? (16 + r) : NQ - 1;
    f32x4 a0 = {0.f, 0.f, 0.f, 0.f}, a1 = {0.f, 0.f, 0.f, 0.f};
    for (int k0 = 0; k0 < HID; k0 += 32) {
      bf16x8 af = *(const bf16x8*)(ktb + (size_t)rowA_c * HID + k0 + kq * 8);
      bf16x8 b0 = *(const bf16x8*)(qpb + (size_t)r * HID + k0 + kq * 8);
      bf16x8 b1 = *(const bf16x8*)(qpb + (size_t)qr1 * HID + k0 + kq * 8);
      a0 = __builtin_amdgcn_mfma_f32_16x16x32_bf16(af, b0, a0, 0, 0, 0);
      a1 = __builtin_amdgcn_mfma_f32_16x16x32_bf16(af, b1, a1, 0, 0, 0);
    }
    const int q0 = lane & 15, mb = (lane >> 4) * 4;
#pragma unroll
    for (int rr = 0; rr < 4; ++rr) {
      const int mA = w * 16 + mb + rr;
      S_lds[mA * SST + q0] = a0[rr] * SCALE;
      if (q0 + 16 < NQ) S_lds[mA * SST + q0 + 16] = a1[rr] * SCALE;
    }
  }
  __syncthreads();
  if (tid < NQ) {
    const int q = tid;
    float m = -1e30f;
    for (int kr = 0; kr < NK; ++kr) m = fmaxf(m, S_lds[kr * SST + q]);
    float s = 0.f;
    for (int kr = 0; kr < NK; ++kr) s += expf(S_lds[kr * SST + q] - m);
    float inv = 1.f / s;
    ushort_t* pq = Pq + (size_t)b * 128 * 128 + q * 128;
    for (int kr = 0; kr < NK; ++kr)
      pq[kr] = f2bf(expf(S_lds[kr * SST + q] - m) * inv);
    for (int kr = NK; kr < 128; ++kr) pq[kr] = 0;  // kill stale KT rows
  } else if (tid >= 32 && tid < 32 + NK) {
    const int kr = tid - 32;
    float m = -1e30f;
#pragma unroll
    for (int q = 0; q < NQ; ++q) m = fmaxf(m, S_lds[kr * SST + q]);
    float s = 0.f;
    float e[NQ];
#pragma unroll
    for (int q = 0; q < NQ; ++q) {
      e[q] = expf(S_lds[kr * SST + q] - m);
      s += e[q];
    }
    float inv = 1.f / s;
    ushort_t* pk = Pk + (size_t)b * 128 * 32 + kr * 32;
#pragma unroll
    for (int q = 0; q < NQ; ++q) pk[q] = f2bf(e[q] * inv);
    pk[30] = 0;  // kill stale QT rows
    pk[31] = 0;
  }
}

// ---------------- pre-cast kernels ----------------
__global__ __launch_bounds__(256) void gather_all_k(
    const int* __restrict__ qid, const int* __restrict__ kid,
    const float* __restrict__ emb, ushort_t* __restrict__ gq,
    ushort_t* __restrict__ gk) {
  int m = blockIdx.x;
  const int* ids;
  ushort_t* outp;
  if (m < MQT) {
    const int bb = m / 30, slot = m - bb * 30;
    ids = qid + m * 3;
    outp = gq + ((size_t)bb * 32 + slot) * KP;
  } else {
    m -= MQT;
    ids = kid + m * 3;
    outp = gk + (size_t)m * KP;
  }
  const int t = threadIdx.x;
  if (t >= KP / 4) return;
  const int k = t * 4;
  ushort4 o = make_ushort4(0, 0, 0, 0);
  if (k < KIN) {
    const int node = (k >= 600) ? 2 : ((k >= 300) ? 1 : 0);
    const int off = k - node * 300;
    const int id = ids[node];
    float4 v = *(const float4*)(emb + (size_t)id * 300 + off);
    if (v.x != v.x) v.x = 0.f;
    if (v.y != v.y) v.y = 0.f;
    if (v.z != v.z) v.z = 0.f;
    if (v.w != v.w) v.w = 0.f;
    o = make_ushort4(f2bf(v.x), f2bf(v.y), f2bf(v.z), f2bf(v.w));
  }
  *(ushort4*)(outp + k) = o;
}

__global__ __launch_bounds__(256) void tcast4_k(
    const float* __restrict__ q2h_w, const float* __restrict__ k2h_w,
    const float* __restrict__ p1w, const float* __restrict__ p2w,
    ushort_t* __restrict__ q2h_wt, ushort_t* __restrict__ k2h_wt,
    ushort_t* __restrict__ p1wt, ushort_t* __restrict__ p2wt) {
  const int z = blockIdx.z;
  const float* src;
  ushort_t* dst;
  int R, Cc, Rp, Cp;
  if (z == 0)      { src = q2h_w; dst = q2h_wt; R = KIN;  Cc = HID;  Rp = KP;   Cp = HID; }
  else if (z == 1) { src = k2h_w; dst = k2h_wt; R = KIN;  Cc = HID;  Rp = KP;   Cp = HID; }
  else if (z == 2) { src = p1w; dst = p1wt; R = 1024; Cc = HID;  Rp = 1024; Cp = HID; }
  else             { src = p2w; dst = p2wt; R = HID;  Cc = NOUT; Rp = HID;  Cp = NOUTP; }
  const int r0 = blockIdx.y * 32, c0 = blockIdx.x * 32;
  if (r0 >= Rp || c0 >= Cp) return;
  __shared__ float t[32][33];
  const int tx = threadIdx.x & 31, ty = threadIdx.x >> 5;
#pragma unroll
  for (int i = 0; i < 4; ++i) {
    int r = r0 + ty + i * 8, c = c0 + tx;
    t[ty + i * 8][tx] = (r < R && c < Cc) ? src[(size_t)r * Cc + c] : 0.f;
  }
  __syncthreads();
#pragma unroll
  for (int i = 0; i < 4; ++i) {
    int c = c0 + ty + i * 8, r = r0 + tx;
    if (c < Cp && r < Rp) dst[(size_t)c * Rp + r] = f2bf(t[tx][ty + i * 8]);
  }
}

__global__ __launch_bounds__(256) void gcast_swz_k(
    const float* __restrict__ glove, ushort_t* __restrict__ gs) {
  const int ts = blockIdx.x, gp = blockIdx.y;
  ushort_t* dst = gs + ((size_t)gp * NTG + ts) * 4096;
  for (int g = threadIdx.x; g < 512; g += 256) {
    const int o = g * 8;
    const int chunk = o >> 9, kq = (o >> 7) & 3, rl = (o >> 3) & 15;
    const int row = gp * 128 + chunk * 16 + rl;
    const int kb = ts * 32 + kq * 8;
    ushort_t tmp[8];
    if (kb + 8 <= NOUT) {
      const float* s = glove + (size_t)row * NOUT + kb;
      float2 a0 = *(const float2*)(s + 0);
      float2 a1 = *(const float2*)(s + 2);
      float2 a2 = *(const float2*)(s + 4);
      float2 a3 = *(const float2*)(s + 6);
      tmp[0] = f2bf(a0.x); tmp[1] = f2bf(a0.y);
      tmp[2] = f2bf(a1.x); tmp[3] = f2bf(a1.y);
      tmp[4] = f2bf(a2.x); tmp[5] = f2bf(a2.y);
      tmp[6] = f2bf(a3.x); tmp[7] = f2bf(a3.y);
    } else {
#pragma unroll
      for (int j = 0; j < 8; ++j) {
        const int k = kb + j;
        tmp[j] = (k < NOUT) ? f2bf(glove[(size_t)row * NOUT + k]) : (ushort_t)0;
      }
    }
    *(ushort4*)(dst + o) = make_ushort4(tmp[0], tmp[1], tmp[2], tmp[3]);
    *(ushort4*)(dst + o + 4) = make_ushort4(tmp[4], tmp[5], tmp[6], tmp[7]);
  }
}

__global__ __launch_bounds__(128) void castrows_k(
    const float* __restrict__ Wk, const float* __restrict__ Wq,
    ushort_t* __restrict__ Wkr, ushort_t* __restrict__ Wqr) {
  const int idx = blockIdx.x;
  const int mat = idx >> 9, row = idx & 511;
  const float* src = (mat < 3 ? Wk + (size_t)mat * HID * HID
                              : Wq + (size_t)(mat - 3) * HID * HID) + (size_t)row * HID;
  ushort_t* dst = (mat < 3 ? Wkr + (size_t)mat * HID * HID
                           : Wqr + (size_t)(mat - 3) * HID * HID) + (size_t)row * HID;
  const int k = threadIdx.x * 4;
  float4 v = *(const float4*)(src + k);
  *(ushort4*)(dst + k) = make_ushort4(f2bf(v.x), f2bf(v.y), f2bf(v.z), f2bf(v.w));
}

// ---------------- fused boundary: parallel row-norms ----------------
__global__ __launch_bounds__(512) void finale_k(
    const ushort_t* __restrict__ Kb, const ushort_t* __restrict__ Qb,
    ushort_t* __restrict__ lastb, const float* __restrict__ curv) {
  const int b = blockIdx.x, tid = threadIdx.x;
  const int w = tid >> 6, lane = tid & 63;
  const float c = curv[NLAYERS];
  const float Kc = 1.f / c, sqrtK = sqrtf(Kc);
  __shared__ float fsc[NK + NQ];
  __shared__ float fst[NK + NQ];
  const ushort_t* xkp = Kb + (size_t)b * NK * HID;
  const ushort_t* xqp = Qb + (size_t)b * 32 * HID;

  for (int r = w; r < NK + NQ; r += 8) {
    const ushort_t* row =
        (r < NK) ? (xkp + (size_t)r * HID) : (xqp + (size_t)(r - NK) * HID);
    bf16x8 v = *(const bf16x8*)(row + lane * 8);
    float ss = 0.f;
#pragma unroll
    for (int j = 0; j < 8; ++j) {
      float t = bf2f((unsigned short)v[j]);
      ss = fmaf(t, t, ss);
    }
    ss = waveReduceSum(ss);
    if (lane == 0) {
      float n = fmaxf(sqrtf(ss), 1e-15f);
      float f = sqrtK * sinhf(n / sqrtK) / n;
      fsc[r] = f;
      fst[r] = sqrtf(fmaxf(Kc + f * f * ss, 1e-7f));
    }
  }
  __syncthreads();

  float mk, mq;
  if (tid == 0) {
    float sk = 0.f, sq2 = 0.f;
    for (int r = 0; r < NK; ++r) sk += fst[r];
    for (int r = 0; r < NQ; ++r) sq2 += fst[NK + r];
    mk = sk;
    mq = sq2;
  } else {
    float sk = 0.f, sq2 = 0.f;
    for (int r = 0; r < NK; ++r)
      sk = fmaf(fsc[r], bf2f(xkp[(size_t)r * HID + tid]), sk);
    for (int r = 0; r < NQ; ++r)
      sq2 = fmaf(fsc[NK + r], bf2f(xqp[(size_t)r * HID + tid]), sq2);
    mk = sk;
    mq = sq2;
  }
  mk *= (1.f / NK);
  mq *= (1.f / NQ);

  float sq = ((tid == 0) ? 0.f : mk * mk) + mq * mq;
  float ssall = blockReduceSum512(sq);
  __shared__ float x0sh;
  if (tid == 0) x0sh = mk;
  __syncthreads();
  const float x0 = x0sh;
  const float n = fmaxf(sqrtf(ssall), 1e-15f);
  const float theta = fmaxf(x0 / sqrtK, 1.f + 1e-7f);
  const float rr = sqrtK * acoshf(theta) / n;
  ushort_t* ob = lastb + (size_t)b * 1024;
  ob[tid] = (tid == 0) ? (ushort_t)0 : f2bf(rr * mk);
  ob[512 + tid] = f2bf(rr * mq);
}

// ---------------- tail: 2-pass online log-softmax ----------------
__global__ __launch_bounds__(512) void logsoftmax_k(float* __restrict__ x) {
  const int b = blockIdx.x, tid = threadIdx.x;
  float4* row = (float4*)(x + (size_t)b * NANS);
  float m = -3.4e38f, s = 0.f;
  for (int i = tid; i < NANS / 4; i += 512) {
    float4 v = row[i];
    float lm = fmaxf(fmaxf(v.x, v.y), fmaxf(v.z, v.w));
    float nm = fmaxf(m, lm);
    s = s * expf(m - nm) + expf(v.x - nm) + expf(v.y - nm) +
        expf(v.z - nm) + expf(v.w - nm);
    m = nm;
  }
#pragma unroll
  for (int o = 32; o > 0; o >>= 1) {
    float mo = __shfl_xor(m, o);
    float so = __shfl_xor(s, o);
    float nm = fmaxf(m, mo);
    s = s * expf(m - nm) + so * expf(mo - nm);
    m = nm;
  }
  __shared__ float smm[8], sms[8];
  const int w = tid >> 6, lane = tid & 63;
  if (lane == 0) { smm[w] = m; sms[w] = s; }
  __syncthreads();
  float gm = smm[0], gs = sms[0];
#pragma unroll
  for (int i = 1; i < 8; ++i) {
    float nm = fmaxf(gm, smm[i]);
    gs = gs * expf(gm - nm) + sms[i] * expf(smm[i] - nm);
    gm = nm;
  }
  const float lse = gm + logf(gs);
  for (int i = tid; i < NANS / 4; i += 512) {
    float4 v = row[i];
    v.x -= lse; v.y -= lse; v.z -= lse; v.w -= lse;
    row[i] = v;
  }
}

// ---------------- launch ----------------
extern "C" void kernel_launch(void* const* d_in, const int* in_sizes, int n_in,
                              void* d_out, int out_size, void* d_ws, size_t ws_size,
                              hipStream_t stream) {
  const int* qid = (const int*)d_in[0];
  const int* kid = (const int*)d_in[1];
  const float* emb = (const float*)d_in[2];
  const float* q2h_w = (const float*)d_in[3];
  const float* q2h_b = (const float*)d_in[4];
  const float* k2h_w = (const float*)d_in[5];
  const float* k2h_b = (const float*)d_in[6];
  const float* Wk = (const float*)d_in[7];
  const float* Wq = (const float*)d_in[8];
  const float* curv = (const float*)d_in[9];
  const float* p1w = (const float*)d_in[10];
  const float* p1b = (const float*)d_in[11];
  const float* p2w = (const float*)d_in[12];
  const float* p2b = (const float*)d_in[13];
  const float* glove = (const float*)d_in[14];
  float* out = (float*)d_out;

  // ---- workspace layout (all bf16 / u16) ----
  ushort_t* u = (ushort_t*)d_ws;
  ushort_t* Ks0 = u;                               // [25600][512] packed 100/b
  ushort_t* Ks1 = Ks0 + (size_t)MKT * HID;
  ushort_t* KsT0 = Ks1 + (size_t)MKT * HID;        // [256][512][128]
  ushort_t* KsT1 = KsT0 + (size_t)BATCH * HID * 128;
  ushort_t* Qs0 = KsT1 + (size_t)BATCH * HID * 128;  // [8192][512] (32/b)
  ushort_t* Qs1 = Qs0 + (size_t)MQ32 * HID;
  ushort_t* QsT0 = Qs1 + (size_t)MQ32 * HID;         // [256][512][32]
  ushort_t* QsT1 = QsT0 + (size_t)BATCH * HID * 32;
  ushort_t* Qps = QsT1 + (size_t)BATCH * HID * 32;   // [8192][512]
  ushort_t* Pk = Qps + (size_t)MQ32 * HID;           // [256][128][32]
  ushort_t* Pq = Pk + (size_t)BATCH * 128 * 32;      // [256][128][128]
  ushort_t* gq = Pq + (size_t)BATCH * 128 * 128;     // [8192][928]
  ushort_t* gk = gq + (size_t)MQ32 * KP;             // [25600][928]
  ushort_t* q2h_wt = gk + (size_t)MKT * KP;
  ushort_t* k2h_wt = q2h_wt + (size_t)HID * KP;
  ushort_t* Wkr = k2h_wt + (size_t)HID * KP;
  ushort_t* Wqr = Wkr + (size_t)NLAYERS * HID * HID;
  ushort_t* Mb = Wqr + (size_t)NLAYERS * HID * HID;
  ushort_t* p1wt = Mb + (size_t)NLAYERS * HID * HID;
  ushort_t* p2wt = p1wt + (size_t)HID * 1024;
  ushort_t* lastb = p2wt + (size_t)NOUTP * HID;
  ushort_t* h1b = lastb + (size_t)BATCH * 1024;
  ushort_t* o2b = h1b + (size_t)BATCH * HID;
  ushort_t* gsw = o2b + (size_t)BATCH * NOUTP;

  // ---- pre-casts ----
  gather_all_k<<<MQT + MKT, 256, 0, stream>>>(qid, kid, emb, gq, gk);
  tcast4_k<<<dim3(16, 32, 4), 256, 0, stream>>>(
      q2h_w, k2h_w, p1w, p2w, q2h_wt, k2h_wt, p1wt, p2wt);
  castrows_k<<<6 * HID, 128, 0, stream>>>(Wk, Wq, Wkr, Wqr);
  gcast_swz_k<<<dim3(NTG, 250), 256, 0, stream>>>(glove, gsw);

  // ---- M_i = Wk_i @ Wq_i^T (bf16 out), batched over z ----
  mfma_gemm2<0, 0, 0, 1, 0, 0, 0, 0><<<dim3(HID / 128, HID / 128, NLAYERS), 256, 0, stream>>>(
      Wkr, Wqr, nullptr, nullptr, Mb, nullptr, nullptr, 128, 128, 0, HID / 128,
      Wkr, Wqr, nullptr, nullptr, Mb, nullptr, nullptr, 128, 128, 0,
      (size_t)HID * HID, (size_t)HID * HID, (size_t)HID * HID, HID, HID, HID, 128);

  // ---- input projections: Q part (32/b) then K part (100/b); emit T states
  mfma_gemm2<0, 1, 0, 1, 1, 0, 0, 1><<<dim3(HID / 128, MQ32 / 128 + MKT / 128), 256, 0, stream>>>(
      gq, q2h_wt, q2h_b, nullptr, Qs0, nullptr, QsT0, 32, 32, (size_t)HID * 32, MQ32 / 128,
      gk, k2h_wt, k2h_b, nullptr, Ks0, nullptr, KsT0, 100, 128, (size_t)HID * 128,
      0, 0, 0, HID, KP, HID, 128);

  // ---- layers in tangent space ----
  ushort_t *Kc = Ks0, *Kn = Ks1, *KcT = KsT0, *KnT = KsT1;
  ushort_t *Qc = Qs0, *Qn = Qs1, *QcT = QsT0, *QnT = QsT1;
  for (int i = 0; i < NLAYERS; ++i) {
    // qp' = qt @ M_i^T  [8192][512]
    mfma_gemm2<0, 0, 0, 1, 0, 0, 0, 0><<<dim3(HID / 128, MQ32 / 128), 256, 0, stream>>>(
        Qc, Mb + (size_t)i * HID * HID, nullptr, nullptr, Qps, nullptr, nullptr,
        128, 128, 0, MQ32 / 128,
        Qc, Mb + (size_t)i * HID * HID, nullptr, nullptr, Qps, nullptr, nullptr,
        128, 128, 0, 0, 0, 0, HID, HID, HID, 128);
    // S + softmaxes -> Pk, Pq
    s_softmax_k<<<BATCH, 512, 0, stream>>>(Kc, Qps, Pk, Pq);
    // att_k = Pk @ qt^T + kt  -> Kn (+KnT)
    mfma_gemm2<0, 0, 0, 1, 0, 0, 1, 1><<<dim3(HID / 128, 1, BATCH), 256, 0, stream>>>(
        Pk, QcT, nullptr, nullptr, Kn, Kc, KnT, 128, 128, (size_t)HID * 128, 1,
        Pk, QcT, nullptr, nullptr, Kn, Kc, KnT, 128, 128, (size_t)HID * 128,
        (size_t)128 * 32, (size_t)HID * 32, (size_t)NK * HID, HID, 32, HID, 100);
    // att_q = Pq @ kt^T + qt  -> Qn (+QnT)
    mfma_gemm2<0, 0, 0, 1, 0, 0, 1, 1><<<dim3(HID / 128, 1, BATCH), 256, 0, stream>>>(
        Pq, KcT, nullptr, nullptr, Qn, Qc, QnT, 128, 32, (size_t)HID * 32, 1,
        Pq, KcT, nullptr, nullptr, Qn, Qc, QnT, 128, 32, (size_t)HID * 32,
        (size_t)128 * 128, (size_t)HID * 128, (size_t)32 * HID, HID, 128, HID, 32);
    ushort_t* t;
    t = Kc; Kc = Kn; Kn = t;
    t = KcT; KcT = KnT; KnT = t;
    t = Qc; Qc = Qn; Qn = t;
    t = QcT; QcT = QnT; QnT = t;
  }

  // ---- fused boundary (expproj + mean + logmap) -> lastb bf16 ----
  finale_k<<<BATCH, 512, 0, stream>>>(Kc, Qc, lastb, curv);

  // ---- head (all MFMA bf16) ----
  mfma_gemm2<0, 1, 0, 1, 0, 1, 0, 0><<<dim3(HID / 128, BATCH / 128), 256, 0, stream>>>(
      lastb, p1wt, p1b, nullptr, h1b, nullptr, nullptr, 128, 128, 0, BATCH / 128,
      lastb, p1wt, p1b, nullptr, h1b, nullptr, nullptr, 128, 128, 0,
      0, 0, 0, HID, 1024, HID, 128);
  mfma_gemm2<0, 1, 0, 1, 0, 0, 0, 0><<<dim3(NOUTP / 128, BATCH / 128), 256, 0, stream>>>(
      h1b, p2wt, p2b, nullptr, o2b, nullptr, nullptr, 128, 128, 0, BATCH / 128,
      h1b, p2wt, p2b, nullptr, o2b, nullptr, nullptr, 128, 128, 0,
      0, 0, 0, NOUTP, HID, NOUT, 128);
  // sim: B = swizzled glove bf16
  mfma_gemm2<1, 0, 1, 0, 0, 0, 0, 0><<<dim3(NANS / 128, BATCH / 128), 256, 0, stream>>>(
      o2b, gsw, nullptr, out, nullptr, nullptr, nullptr, 128, 128, 0, BATCH / 128,
      o2b, gsw, nullptr, out, nullptr, nullptr, nullptr, 128, 128, 0,
      0, 0, 0, NANS, NOUTP, NANS, 128);
  logsoftmax_k<<<BATCH, 512, 0, stream>>>(out);
}

// Round 19
// 417.017 us; speedup vs baseline: 1.3870x; 1.3870x over previous
//
#include <hip/hip_runtime.h>
#include <math.h>

// Problem constants (from setup_inputs)
#define BATCH 256
#define NQ 30
#define NK 100
#define HID 512
#define WORD 300
#define KIN 900          // WORD*3
#define KP 928           // KIN padded to multiple of 32
#define NANS 32000
#define NOUT 300
#define NOUTP 384        // NOUT padded (MFMA K for sim)
#define NTG 12           // NOUTP/32
#define NLAYERS 3
#define MQT (BATCH * NQ)   // 7680
#define MKT (BATCH * NK)   // 25600
#define SCALE 0.044194173824159216f  // 1/sqrt(512)
#define CLDST 136          // C-tile LDS row stride (u16)
#define SST 36             // S LDS row stride (floats); Pk overlay stride 72 u16
#define PQLD 136           // Pq row stride (u16)
#define QTS 256            // qt-half LDS row stride (u16), wave-linear staging

typedef __attribute__((ext_vector_type(8))) short bf16x8;
typedef __attribute__((ext_vector_type(4))) float f32x4;
typedef unsigned short ushort_t;

__device__ __forceinline__ unsigned short f2bf(float f) {
  unsigned int u = __float_as_uint(f);
  u = (u + 0x7FFF + ((u >> 16) & 1)) >> 16;  // RNE
  return (unsigned short)u;
}
__device__ __forceinline__ float bf2f(unsigned short s) {
  return __uint_as_float(((unsigned int)s) << 16);
}

typedef const __attribute__((address_space(1))) unsigned int* gas_u32;
typedef __attribute__((address_space(3))) unsigned int* las_u32;
__device__ __forceinline__ void gld_lds16(const void* g, void* l) {
  __builtin_amdgcn_global_load_lds((gas_u32)g, (las_u32)l, 16, 0, 0);
}

// bijective XCD swizzle (m204)
__device__ __forceinline__ int xcd_swz_linear() {
  const int nwg = gridDim.x * gridDim.y;
  const int orig = blockIdx.y * gridDim.x + blockIdx.x;
  const int q = nwg >> 3, r = nwg & 7;
  const int xcd = orig & 7, idx = orig >> 3;
  return (xcd < r ? xcd * (q + 1) : r * (q + 1) + (xcd - r) * q) + idx;
}

// ---------------- reduction helpers ----------------
__device__ __forceinline__ float waveReduceSum(float v) {
#pragma unroll
  for (int o = 32; o > 0; o >>= 1) v += __shfl_xor(v, o);
  return v;
}
__device__ float blockReduceSum512(float v) {
  __shared__ float sm[8];
  int lane = threadIdx.x & 63, w = threadIdx.x >> 6;
  v = waveReduceSum(v);
  if (lane == 0) sm[w] = v;
  __syncthreads();
  float r = 0.f;
#pragma unroll
  for (int i = 0; i < 8; ++i) r += sm[i];
  __syncthreads();
  return r;
}

// ---------------- bf16 MFMA GEMM: 2-phase dbuf + LDS-staged bf16 epilogue --
template <int SWZB, int BIAS, int OUTF32, int OUTBF16, int ZC0, int RELU>
__global__ __launch_bounds__(256) void mfma_gemm2(
    const ushort_t* __restrict__ A1, const ushort_t* __restrict__ Bt1,
    const float* __restrict__ bias1, float* __restrict__ C1,
    ushort_t* __restrict__ Cb1, int M1b,
    const ushort_t* __restrict__ A2, const ushort_t* __restrict__ Bt2,
    const float* __restrict__ bias2, float* __restrict__ C2,
    ushort_t* __restrict__ Cb2,
    size_t zsA, size_t zsB, size_t zsC,
    int N, int K, int nbias) {
  __shared__ __align__(16) ushort_t smem[128 * CLDST];
  const int wg = xcd_swz_linear();
  const int bx = wg % gridDim.x, by = wg / gridDim.x;
  const int z = blockIdx.z;
  const bool sel = (by >= M1b);
  const ushort_t* A = (sel ? A2 : A1) + z * zsA;
  const ushort_t* Bt = (sel ? Bt2 : Bt1) + z * zsB;
  const float* bias = sel ? bias2 : bias1;
  float* C = (sel ? C2 : C1);
  ushort_t* Cb = (sel ? Cb2 : Cb1);
  if (C) C += z * zsC;
  if (Cb) Cb += z * zsC;
  const int row0 = (sel ? (by - M1b) : by) * 128;
  const int col0 = bx * 128;

  const int tid = threadIdx.x;
  const int lane = tid & 63, w = tid >> 6;
  const int wr = w >> 1, wc = w & 1;
  const int s_r = lane & 15, s_kq = lane >> 4;
  const int nt = K / 32;

  const size_t a_src0 = (size_t)(row0 + (w * 2 + 0) * 16 + s_r) * K + s_kq * 8;
  const size_t a_src1 = (size_t)(row0 + (w * 2 + 1) * 16 + s_r) * K + s_kq * 8;
  const size_t b_lin0 = (size_t)(col0 + (w * 2 + 0) * 16 + s_r) * K + s_kq * 8;
  const size_t b_lin1 = (size_t)(col0 + (w * 2 + 1) * 16 + s_r) * K + s_kq * 8;
  const size_t b_swz0 = ((size_t)(col0 >> 7) * nt) * 4096 + (w * 2 + 0) * 512 + lane * 8;
  const size_t b_swz1 = b_swz0 + 512;

  auto stageAB = [&](int t, int bsel) {
    const int k0 = t * 32;
    ushort_t* Ab = smem + bsel * 4096;
    ushort_t* Bb = smem + 8192 + bsel * 4096;
    gld_lds16(A + a_src0 + k0, Ab + (w * 2 + 0) * 512);
    gld_lds16(A + a_src1 + k0, Ab + (w * 2 + 1) * 512);
    if (SWZB) {
      gld_lds16(Bt + b_swz0 + (size_t)t * 4096, Bb + (w * 2 + 0) * 512);
      gld_lds16(Bt + b_swz1 + (size_t)t * 4096, Bb + (w * 2 + 1) * 512);
    } else {
      gld_lds16(Bt + b_lin0 + k0, Bb + (w * 2 + 0) * 512);
      gld_lds16(Bt + b_lin1 + k0, Bb + (w * 2 + 1) * 512);
    }
  };

  f32x4 acc[4][4];
#pragma unroll
  for (int i = 0; i < 4; ++i)
#pragma unroll
    for (int j = 0; j < 4; ++j) acc[i][j] = (f32x4){0.f, 0.f, 0.f, 0.f};

  stageAB(0, 0);
  __syncthreads();
  for (int t = 0; t < nt; ++t) {
    const int cur = t & 1;
    if (t + 1 < nt) stageAB(t + 1, cur ^ 1);
    const ushort_t* Ab = smem + cur * 4096;
    const ushort_t* Bb = smem + 8192 + cur * 4096;
    bf16x8 af[4], bfr[4];
#pragma unroll
    for (int mi = 0; mi < 4; ++mi)
      af[mi] = *(const bf16x8*)(Ab + (wr * 4 + mi) * 512 + lane * 8);
#pragma unroll
    for (int nj = 0; nj < 4; ++nj)
      bfr[nj] = *(const bf16x8*)(Bb + (wc * 4 + nj) * 512 + lane * 8);
#pragma unroll
    for (int mi = 0; mi < 4; ++mi)
#pragma unroll
      for (int nj = 0; nj < 4; ++nj)
        acc[mi][nj] = __builtin_amdgcn_mfma_f32_16x16x32_bf16(
            af[mi], bfr[nj], acc[mi][nj], 0, 0, 0);
    __syncthreads();
  }

  if (OUTBF16) {
#pragma unroll
    for (int nj = 0; nj < 4; ++nj) {
      const int nl = wc * 64 + nj * 16 + (lane & 15);
      const int n = col0 + nl;
      const float bb = BIAS ? ((n < nbias) ? bias[n] : 0.f) : 0.f;
#pragma unroll
      for (int mi = 0; mi < 4; ++mi) {
        f32x4 v = acc[mi][nj];
#pragma unroll
        for (int r = 0; r < 4; ++r) {
          const int ml = wr * 64 + mi * 16 + (lane >> 4) * 4 + r;
          float val = v[r] + bb;
          if (RELU) val = fmaxf(val, 0.f);
          if (ZC0 && n == 0) val = 0.f;
          smem[ml * CLDST + nl] = f2bf(val);
        }
      }
    }
    __syncthreads();
#pragma unroll
    for (int j = 0; j < 8; ++j) {
      const int e = j * 2048 + tid * 8;
      const int ml = e >> 7, nl = e & 127;
      uint4 v = *(const uint4*)(smem + ml * CLDST + nl);
      *(uint4*)(Cb + (size_t)(row0 + ml) * N + col0 + nl) = v;
    }
  }
  if (OUTF32) {
#pragma unroll
    for (int nj = 0; nj < 4; ++nj) {
      const int n = col0 + wc * 64 + nj * 16 + (lane & 15);
      const float bb = BIAS ? ((n < nbias) ? bias[n] : 0.f) : 0.f;
#pragma unroll
      for (int mi = 0; mi < 4; ++mi) {
        f32x4 v = acc[mi][nj];
#pragma unroll
        for (int r = 0; r < 4; ++r) {
          const int m = row0 + wr * 64 + mi * 16 + (lane >> 4) * 4 + r;
          float val = v[r] + bb;
          if (RELU) val = fmaxf(val, 0.f);
          if (ZC0 && n == 0) val = 0.f;
          C[(size_t)m * N + n] = val;
        }
      }
    }
  }
}

// ---------------- pre-cast kernels ----------------
__global__ __launch_bounds__(256) void gather_all_k(
    const int* __restrict__ qid, const int* __restrict__ kid,
    const float* __restrict__ emb, ushort_t* __restrict__ gq,
    ushort_t* __restrict__ gk) {
  int m = blockIdx.x;
  const int* ids;
  ushort_t* outp;
  if (m < MQT) {
    ids = qid + m * 3;
    outp = gq + (size_t)m * KP;
  } else {
    m -= MQT;
    ids = kid + m * 3;
    outp = gk + (size_t)m * KP;
  }
  const int t = threadIdx.x;
  if (t >= KP / 4) return;
  const int k = t * 4;
  ushort4 o = make_ushort4(0, 0, 0, 0);
  if (k < KIN) {
    const int node = (k >= 600) ? 2 : ((k >= 300) ? 1 : 0);
    const int off = k - node * 300;
    const int id = ids[node];
    float4 v = *(const float4*)(emb + (size_t)id * 300 + off);
    if (v.x != v.x) v.x = 0.f;
    if (v.y != v.y) v.y = 0.f;
    if (v.z != v.z) v.z = 0.f;
    if (v.w != v.w) v.w = 0.f;
    o = make_ushort4(f2bf(v.x), f2bf(v.y), f2bf(v.z), f2bf(v.w));
  }
  *(ushort4*)(outp + k) = o;
}

__global__ __launch_bounds__(256) void tcast4_k(
    const float* __restrict__ q2h_w, const float* __restrict__ k2h_w,
    const float* __restrict__ p1w, const float* __restrict__ p2w,
    ushort_t* __restrict__ q2h_wt, ushort_t* __restrict__ k2h_wt,
    ushort_t* __restrict__ p1wt, ushort_t* __restrict__ p2wt) {
  const int z = blockIdx.z;
  const float* src;
  ushort_t* dst;
  int R, Cc, Rp, Cp;
  if (z == 0)      { src = q2h_w; dst = q2h_wt; R = KIN;  Cc = HID;  Rp = KP;   Cp = HID; }
  else if (z == 1) { src = k2h_w; dst = k2h_wt; R = KIN;  Cc = HID;  Rp = KP;   Cp = HID; }
  else if (z == 2) { src = p1w; dst = p1wt; R = 1024; Cc = HID;  Rp = 1024; Cp = HID; }
  else             { src = p2w; dst = p2wt; R = HID;  Cc = NOUT; Rp = HID;  Cp = NOUTP; }
  const int r0 = blockIdx.y * 32, c0 = blockIdx.x * 32;
  if (r0 >= Rp || c0 >= Cp) return;
  __shared__ float t[32][33];
  const int tx = threadIdx.x & 31, ty = threadIdx.x >> 5;
#pragma unroll
  for (int i = 0; i < 4; ++i) {
    int r = r0 + ty + i * 8, c = c0 + tx;
    t[ty + i * 8][tx] = (r < R && c < Cc) ? src[(size_t)r * Cc + c] : 0.f;
  }
  __syncthreads();
#pragma unroll
  for (int i = 0; i < 4; ++i) {
    int c = c0 + ty + i * 8, r = r0 + tx;
    if (c < Cp && r < Rp) dst[(size_t)c * Rp + r] = f2bf(t[tx][ty + i * 8]);
  }
}

__global__ __launch_bounds__(256) void gcast_swz_k(
    const float* __restrict__ glove, ushort_t* __restrict__ gs) {
  const int ts = blockIdx.x, gp = blockIdx.y;
  ushort_t* dst = gs + ((size_t)gp * NTG + ts) * 4096;
  for (int g = threadIdx.x; g < 512; g += 256) {
    const int o = g * 8;
    const int chunk = o >> 9, kq = (o >> 7) & 3, rl = (o >> 3) & 15;
    const int row = gp * 128 + chunk * 16 + rl;
    const int kb = ts * 32 + kq * 8;
    ushort_t tmp[8];
    if (kb + 8 <= NOUT) {
      const float* s = glove + (size_t)row * NOUT + kb;
      float2 a0 = *(const float2*)(s + 0);
      float2 a1 = *(const float2*)(s + 2);
      float2 a2 = *(const float2*)(s + 4);
      float2 a3 = *(const float2*)(s + 6);
      tmp[0] = f2bf(a0.x); tmp[1] = f2bf(a0.y);
      tmp[2] = f2bf(a1.x); tmp[3] = f2bf(a1.y);
      tmp[4] = f2bf(a2.x); tmp[5] = f2bf(a2.y);
      tmp[6] = f2bf(a3.x); tmp[7] = f2bf(a3.y);
    } else {
#pragma unroll
      for (int j = 0; j < 8; ++j) {
        const int k = kb + j;
        tmp[j] = (k < NOUT) ? f2bf(glove[(size_t)row * NOUT + k]) : (ushort_t)0;
      }
    }
    *(ushort4*)(dst + o) = make_ushort4(tmp[0], tmp[1], tmp[2], tmp[3]);
    *(ushort4*)(dst + o + 4) = make_ushort4(tmp[4], tmp[5], tmp[6], tmp[7]);
  }
}

__global__ __launch_bounds__(128) void castrows_k(
    const float* __restrict__ Wk, const float* __restrict__ Wq,
    ushort_t* __restrict__ Wkr, ushort_t* __restrict__ Wqr) {
  const int idx = blockIdx.x;
  const int mat = idx >> 9, row = idx & 511;
  const float* src = (mat < 3 ? Wk + (size_t)mat * HID * HID
                              : Wq + (size_t)(mat - 3) * HID * HID) + (size_t)row * HID;
  ushort_t* dst = (mat < 3 ? Wkr + (size_t)mat * HID * HID
                           : Wqr + (size_t)(mat - 3) * HID * HID) + (size_t)row * HID;
  const int k = threadIdx.x * 4;
  float4 v = *(const float4*)(src + k);
  *(ushort4*)(dst + k) = make_ushort4(f2bf(v.x), f2bf(v.y), f2bf(v.z), f2bf(v.w));
}

// ---------------- fused attention v6: 2 column-chunk blocks per batch ------
// grid (2, BATCH), 512 threads, LDS ~40KB (2 blocks/CU).
// kt stays in GLOBAL (L2/L3-resident): phase-1 A-frags = vector loads,
// phase-4 B-frags + residuals = scalar gathers. qt half staged in LDS.
// phase1 (waves 0-6): S = SCALE*kt@qp'^T -> S_lds (duplicated per chunk)
// phase2: softmaxes -> Pq (bf16) + Pk (bf16 overlay on S)
// phase3 (waves 0-3): att_k = Pk@qt + kt for this chunk's 256 cols (MFMA)
// phase4 (waves 4-7): att_q = Pq@kt + qt for this chunk's 256 cols (MFMA)
__global__ __launch_bounds__(512) void att_fused_k(
    const ushort_t* __restrict__ Qp, const ushort_t* __restrict__ Ktc,
    const ushort_t* __restrict__ Qc, ushort_t* __restrict__ Kn,
    ushort_t* __restrict__ Qn) {
  const int b = blockIdx.y;
  const int c0 = blockIdx.x * 256;
  __shared__ __align__(16) float S_lds[112 * SST];     // 16128 B (Pk overlay)
  __shared__ __align__(16) ushort_t Pq[32 * PQLD];     // 8704 B
  __shared__ __align__(16) ushort_t qts[NQ * QTS];     // 15360 B (qt half)
  const int tid = threadIdx.x;
  const int w = tid >> 6, lane = tid & 63;
  const ushort_t* ktb = Ktc + (size_t)b * NK * HID;
  const ushort_t* qtg = Qc + (size_t)b * NQ * HID;

  // stage qt half: wave-linear dest (one wave covers 2 rows of 32 chunks)
  for (int e = tid; e < NQ * 32; e += 512) {
    const int r = e >> 5, c16 = e & 31;
    gld_lds16(qtg + (size_t)r * HID + c0 + c16 * 8, qts + r * QTS + c16 * 8);
  }

  // ---- phase 1: S (waves 0-6), A-frags from GLOBAL kt ----
  if (w < 7) {
    const int r = lane & 15, kq = lane >> 4;
    const ushort_t* qpb = Qp + (size_t)b * NQ * HID;
    const int rowA = w * 16 + r;
    const int rowA_c = (rowA < NK) ? rowA : (NK - 1);
    const int qr1 = (16 + r) < NQ ? (16 + r) : NQ - 1;
    f32x4 a0 = {0.f, 0.f, 0.f, 0.f}, a1 = {0.f, 0.f, 0.f, 0.f};
    for (int k0 = 0; k0 < HID; k0 += 32) {
      bf16x8 af = *(const bf16x8*)(ktb + (size_t)rowA_c * HID + k0 + kq * 8);
      bf16x8 b0 = *(const bf16x8*)(qpb + (size_t)r * HID + k0 + kq * 8);
      bf16x8 b1 = *(const bf16x8*)(qpb + (size_t)qr1 * HID + k0 + kq * 8);
      a0 = __builtin_amdgcn_mfma_f32_16x16x32_bf16(af, b0, a0, 0, 0, 0);
      a1 = __builtin_amdgcn_mfma_f32_16x16x32_bf16(af, b1, a1, 0, 0, 0);
    }
    const int q0 = lane & 15, mb = (lane >> 4) * 4;
#pragma unroll
    for (int rr = 0; rr < 4; ++rr) {
      const int mA = w * 16 + mb + rr;
      if (mA < NK) {
        S_lds[mA * SST + q0] = a0[rr] * SCALE;
        if (q0 + 16 < NQ) S_lds[mA * SST + q0 + 16] = a1[rr] * SCALE;
      }
    }
  }
  __syncthreads();
  // ---- phase 2: softmaxes ----
  float e2[NQ];
  float inv2 = 0.f;
  const int kr2 = tid - 32;
  const bool do2b = (kr2 >= 0 && kr2 < NK);
  if (tid < NQ) {
    const int q = tid;
    float m = -1e30f;
    for (int kr = 0; kr < NK; ++kr) m = fmaxf(m, S_lds[kr * SST + q]);
    float s = 0.f;
    for (int kr = 0; kr < NK; ++kr) s += expf(S_lds[kr * SST + q] - m);
    float inv = 1.f / s;
    for (int kr = 0; kr < NK; ++kr)
      Pq[q * PQLD + kr] = f2bf(expf(S_lds[kr * SST + q] - m) * inv);
    for (int kr = NK; kr < 128; ++kr) Pq[q * PQLD + kr] = 0;
  } else if (tid < 32) {
    for (int kr = 0; kr < 128; ++kr) Pq[tid * PQLD + kr] = 0;
  } else if (do2b) {
    float m = -1e30f;
#pragma unroll
    for (int q = 0; q < NQ; ++q) m = fmaxf(m, S_lds[kr2 * SST + q]);
    float s = 0.f;
#pragma unroll
    for (int q = 0; q < NQ; ++q) {
      e2[q] = expf(S_lds[kr2 * SST + q] - m);
      s += e2[q];
    }
    inv2 = 1.f / s;
  }
  __syncthreads();
  ushort_t* Pk = (ushort_t*)S_lds;  // overlay, row stride 72 u16
  if (do2b) {
    ushort_t* prow = Pk + kr2 * 72;
#pragma unroll
    for (int q = 0; q < NQ; ++q) prow[q] = f2bf(e2[q] * inv2);
    prow[30] = 0;
    prow[31] = 0;
  }
  __syncthreads();

  const int cl = lane & 15, g8 = (lane >> 4) * 8;
  if (w < 4) {
    // ---- phase 3: att_k = Pk @ qt + kt; wave owns 64 cols of the chunk ----
    bf16x8 bk[4];
#pragma unroll
    for (int nt = 0; nt < 4; ++nt) {
      const int coll = w * 64 + nt * 16 + cl;  // local (LDS) col
      union { ushort_t u[8]; bf16x8 v; } pb;
#pragma unroll
      for (int j = 0; j < 8; ++j) {
        const int q = g8 + j;
        pb.u[j] = qts[(q < NQ ? q : NQ - 1) * QTS + coll];
      }
      bk[nt] = pb.v;
    }
    ushort_t* kout = Kn + (size_t)b * NK * HID;
#pragma unroll
    for (int mt = 0; mt < 7; ++mt) {
      bf16x8 af = *(const bf16x8*)(Pk + (mt * 16 + cl) * 72 + g8);
      f32x4 ac[4];
#pragma unroll
      for (int nt = 0; nt < 4; ++nt) {
        ac[nt] = (f32x4){0.f, 0.f, 0.f, 0.f};
        ac[nt] = __builtin_amdgcn_mfma_f32_16x16x32_bf16(af, bk[nt], ac[nt], 0, 0, 0);
      }
#pragma unroll
      for (int nt = 0; nt < 4; ++nt) {
        const int col = c0 + w * 64 + nt * 16 + cl;
#pragma unroll
        for (int r = 0; r < 4; ++r) {
          const int row = mt * 16 + (lane >> 4) * 4 + r;
          if (row < NK) {
            float v = ac[nt][r] + bf2f(ktb[(size_t)row * HID + col]);
            kout[(size_t)row * HID + col] = f2bf(v);
          }
        }
      }
    }
  } else {
    // ---- phase 4: att_q = Pq @ kt + qt; wave owns 64 cols of the chunk ----
    const int w4 = w - 4;
    f32x4 aq[2][4];
#pragma unroll
    for (int mt = 0; mt < 2; ++mt)
#pragma unroll
      for (int nt = 0; nt < 4; ++nt) aq[mt][nt] = (f32x4){0.f, 0.f, 0.f, 0.f};
#pragma unroll
    for (int ks = 0; ks < 4; ++ks) {
      bf16x8 bq[4];
#pragma unroll
      for (int nt = 0; nt < 4; ++nt) {
        const int col = c0 + w4 * 64 + nt * 16 + cl;
        union { ushort_t u[8]; bf16x8 v; } pb;
#pragma unroll
        for (int j = 0; j < 8; ++j) {
          const int kr = ks * 32 + g8 + j;
          pb.u[j] = ktb[(size_t)(kr < NK ? kr : NK - 1) * HID + col];
        }
        bq[nt] = pb.v;
      }
#pragma unroll
      for (int mt = 0; mt < 2; ++mt) {
        bf16x8 af = *(const bf16x8*)(Pq + (mt * 16 + cl) * PQLD + ks * 32 + g8);
#pragma unroll
        for (int nt = 0; nt < 4; ++nt)
          aq[mt][nt] = __builtin_amdgcn_mfma_f32_16x16x32_bf16(af, bq[nt], aq[mt][nt], 0, 0, 0);
      }
    }
    ushort_t* qout = Qn + (size_t)b * NQ * HID;
#pragma unroll
    for (int mt = 0; mt < 2; ++mt)
#pragma unroll
      for (int nt = 0; nt < 4; ++nt) {
        const int coll = w4 * 64 + nt * 16 + cl;
        const int col = c0 + coll;
#pragma unroll
        for (int r = 0; r < 4; ++r) {
          const int row = mt * 16 + (lane >> 4) * 4 + r;
          if (row < NQ) {
            float v = aq[mt][nt][r] + bf2f(qts[row * QTS + coll]);
            qout[(size_t)row * HID + col] = f2bf(v);
          }
        }
      }
  }
}

// ---------------- fused boundary: parallel row-norms ----------------
__global__ __launch_bounds__(512) void finale_k(
    const ushort_t* __restrict__ Kb, const ushort_t* __restrict__ Qb,
    ushort_t* __restrict__ lastb, const float* __restrict__ curv) {
  const int b = blockIdx.x, tid = threadIdx.x;
  const int w = tid >> 6, lane = tid & 63;
  const float c = curv[NLAYERS];
  const float Kc = 1.f / c, sqrtK = sqrtf(Kc);
  __shared__ float fsc[NK + NQ];
  __shared__ float fst[NK + NQ];
  const ushort_t* xkp = Kb + (size_t)b * NK * HID;
  const ushort_t* xqp = Qb + (size_t)b * NQ * HID;

  for (int r = w; r < NK + NQ; r += 8) {
    const ushort_t* row =
        (r < NK) ? (xkp + (size_t)r * HID) : (xqp + (size_t)(r - NK) * HID);
    bf16x8 v = *(const bf16x8*)(row + lane * 8);
    float ss = 0.f;
#pragma unroll
    for (int j = 0; j < 8; ++j) {
      float t = bf2f((unsigned short)v[j]);
      ss = fmaf(t, t, ss);
    }
    ss = waveReduceSum(ss);
    if (lane == 0) {
      float n = fmaxf(sqrtf(ss), 1e-15f);
      float f = sqrtK * sinhf(n / sqrtK) / n;
      fsc[r] = f;
      fst[r] = sqrtf(fmaxf(Kc + f * f * ss, 1e-7f));
    }
  }
  __syncthreads();

  float mk, mq;
  if (tid == 0) {
    float sk = 0.f, sq2 = 0.f;
    for (int r = 0; r < NK; ++r) sk += fst[r];
    for (int r = 0; r < NQ; ++r) sq2 += fst[NK + r];
    mk = sk;
    mq = sq2;
  } else {
    float sk = 0.f, sq2 = 0.f;
    for (int r = 0; r < NK; ++r)
      sk = fmaf(fsc[r], bf2f(xkp[(size_t)r * HID + tid]), sk);
    for (int r = 0; r < NQ; ++r)
      sq2 = fmaf(fsc[NK + r], bf2f(xqp[(size_t)r * HID + tid]), sq2);
    mk = sk;
    mq = sq2;
  }
  mk *= (1.f / NK);
  mq *= (1.f / NQ);

  float sq = ((tid == 0) ? 0.f : mk * mk) + mq * mq;
  float ssall = blockReduceSum512(sq);
  __shared__ float x0sh;
  if (tid == 0) x0sh = mk;
  __syncthreads();
  const float x0 = x0sh;
  const float n = fmaxf(sqrtf(ssall), 1e-15f);
  const float theta = fmaxf(x0 / sqrtK, 1.f + 1e-7f);
  const float rr = sqrtK * acoshf(theta) / n;
  ushort_t* ob = lastb + (size_t)b * 1024;
  ob[tid] = (tid == 0) ? (ushort_t)0 : f2bf(rr * mk);
  ob[512 + tid] = f2bf(rr * mq);
}

// ---------------- tail: 2-pass online log-softmax ----------------
__global__ __launch_bounds__(512) void logsoftmax_k(float* __restrict__ x) {
  const int b = blockIdx.x, tid = threadIdx.x;
  float4* row = (float4*)(x + (size_t)b * NANS);
  float m = -3.4e38f, s = 0.f;
  for (int i = tid; i < NANS / 4; i += 512) {
    float4 v = row[i];
    float lm = fmaxf(fmaxf(v.x, v.y), fmaxf(v.z, v.w));
    float nm = fmaxf(m, lm);
    s = s * expf(m - nm) + expf(v.x - nm) + expf(v.y - nm) +
        expf(v.z - nm) + expf(v.w - nm);
    m = nm;
  }
#pragma unroll
  for (int o = 32; o > 0; o >>= 1) {
    float mo = __shfl_xor(m, o);
    float so = __shfl_xor(s, o);
    float nm = fmaxf(m, mo);
    s = s * expf(m - nm) + so * expf(mo - nm);
    m = nm;
  }
  __shared__ float smm[8], sms[8];
  const int w = tid >> 6, lane = tid & 63;
  if (lane == 0) { smm[w] = m; sms[w] = s; }
  __syncthreads();
  float gm = smm[0], gs = sms[0];
#pragma unroll
  for (int i = 1; i < 8; ++i) {
    float nm = fmaxf(gm, smm[i]);
    gs = gs * expf(gm - nm) + sms[i] * expf(smm[i] - nm);
    gm = nm;
  }
  const float lse = gm + logf(gs);
  for (int i = tid; i < NANS / 4; i += 512) {
    float4 v = row[i];
    v.x -= lse; v.y -= lse; v.z -= lse; v.w -= lse;
    row[i] = v;
  }
}

// ---------------- launch ----------------
extern "C" void kernel_launch(void* const* d_in, const int* in_sizes, int n_in,
                              void* d_out, int out_size, void* d_ws, size_t ws_size,
                              hipStream_t stream) {
  const int* qid = (const int*)d_in[0];
  const int* kid = (const int*)d_in[1];
  const float* emb = (const float*)d_in[2];
  const float* q2h_w = (const float*)d_in[3];
  const float* q2h_b = (const float*)d_in[4];
  const float* k2h_w = (const float*)d_in[5];
  const float* k2h_b = (const float*)d_in[6];
  const float* Wk = (const float*)d_in[7];
  const float* Wq = (const float*)d_in[8];
  const float* curv = (const float*)d_in[9];
  const float* p1w = (const float*)d_in[10];
  const float* p1b = (const float*)d_in[11];
  const float* p2w = (const float*)d_in[12];
  const float* p2b = (const float*)d_in[13];
  const float* glove = (const float*)d_in[14];
  float* out = (float*)d_out;

  // ---- workspace layout (all bf16) ----
  ushort_t* u = (ushort_t*)d_ws;
  ushort_t* Ks0 = u;
  ushort_t* Ks1 = Ks0 + (size_t)MKT * HID;
  ushort_t* Qs0 = Ks1 + (size_t)MKT * HID;
  ushort_t* Qs1 = Qs0 + (size_t)MQT * HID;
  ushort_t* Qps = Qs1 + (size_t)MQT * HID;
  ushort_t* gq = Qps + (size_t)MQT * HID;
  ushort_t* gk = gq + (size_t)MQT * KP;
  ushort_t* q2h_wt = gk + (size_t)MKT * KP;
  ushort_t* k2h_wt = q2h_wt + (size_t)HID * KP;
  ushort_t* Wkr = k2h_wt + (size_t)HID * KP;
  ushort_t* Wqr = Wkr + (size_t)NLAYERS * HID * HID;
  ushort_t* Mb = Wqr + (size_t)NLAYERS * HID * HID;
  ushort_t* p1wt = Mb + (size_t)NLAYERS * HID * HID;
  ushort_t* p2wt = p1wt + (size_t)HID * 1024;
  ushort_t* lastb = p2wt + (size_t)NOUTP * HID;
  ushort_t* h1b = lastb + (size_t)BATCH * 1024;
  ushort_t* o2b = h1b + (size_t)BATCH * HID;
  ushort_t* gsw = o2b + (size_t)BATCH * NOUTP;

  // ---- pre-casts ----
  gather_all_k<<<MQT + MKT, 256, 0, stream>>>(qid, kid, emb, gq, gk);
  tcast4_k<<<dim3(16, 32, 4), 256, 0, stream>>>(
      q2h_w, k2h_w, p1w, p2w, q2h_wt, k2h_wt, p1wt, p2wt);
  castrows_k<<<6 * HID, 128, 0, stream>>>(Wk, Wq, Wkr, Wqr);
  gcast_swz_k<<<dim3(NTG, 250), 256, 0, stream>>>(glove, gsw);

  // ---- M_i = Wk_i @ Wq_i^T (bf16 out), batched over z ----
  mfma_gemm2<0, 0, 0, 1, 0, 0><<<dim3(HID / 128, HID / 128, NLAYERS), 256, 0, stream>>>(
      Wkr, Wqr, nullptr, nullptr, Mb, HID / 128,
      Wkr, Wqr, nullptr, nullptr, Mb,
      (size_t)HID * HID, (size_t)HID * HID, (size_t)HID * HID, HID, HID, HID);

  // ---- input projections (merged q+k), fused proj_tan0, bf16 out ----
  mfma_gemm2<0, 1, 0, 1, 1, 0><<<dim3(HID / 128, MQT / 128 + MKT / 128), 256, 0, stream>>>(
      gq, q2h_wt, q2h_b, nullptr, Qs0, MQT / 128,
      gk, k2h_wt, k2h_b, nullptr, Ks0, 0, 0, 0, HID, KP, HID);

  // ---- layers in tangent space ----
  ushort_t* Kc = Ks0;
  ushort_t* Kn = Ks1;
  ushort_t* Qc = Qs0;
  ushort_t* Qn = Qs1;
  for (int i = 0; i < NLAYERS; ++i) {
    mfma_gemm2<0, 0, 0, 1, 0, 0><<<dim3(HID / 128, MQT / 128), 256, 0, stream>>>(
        Qc, Mb + (size_t)i * HID * HID, nullptr, nullptr, Qps, MQT / 128,
        Qc, Mb + (size_t)i * HID * HID, nullptr, nullptr, Qps,
        0, 0, 0, HID, HID, HID);
    att_fused_k<<<dim3(2, BATCH), 512, 0, stream>>>(Qps, Kc, Qc, Kn, Qn);
    ushort_t* t1 = Kc; Kc = Kn; Kn = t1;
    ushort_t* t2 = Qc; Qc = Qn; Qn = t2;
  }

  // ---- fused boundary (expproj + mean + logmap) -> lastb bf16 ----
  finale_k<<<BATCH, 512, 0, stream>>>(Kc, Qc, lastb, curv);

  // ---- head (all MFMA bf16) ----
  mfma_gemm2<0, 1, 0, 1, 0, 1><<<dim3(HID / 128, BATCH / 128), 256, 0, stream>>>(
      lastb, p1wt, p1b, nullptr, h1b, BATCH / 128,
      lastb, p1wt, p1b, nullptr, h1b, 0, 0, 0, HID, 1024, HID);
  mfma_gemm2<0, 1, 0, 1, 0, 0><<<dim3(NOUTP / 128, BATCH / 128), 256, 0, stream>>>(
      h1b, p2wt, p2b, nullptr, o2b, BATCH / 128,
      h1b, p2wt, p2b, nullptr, o2b, 0, 0, 0, NOUTP, HID, NOUT);
  // sim: B = swizzled glove bf16
  mfma_gemm2<1, 0, 1, 0, 0, 0><<<dim3(NANS / 128, BATCH / 128), 256, 0, stream>>>(
      o2b, gsw, nullptr, out, nullptr, BATCH / 128,
      o2b, gsw, nullptr, out, nullptr, 0, 0, 0, NANS, NOUTP, NANS);
  logsoftmax_k<<<BATCH, 512, 0, stream>>>(out);
}

// Round 20
// 397.712 us; speedup vs baseline: 1.4543x; 1.0485x over previous
//
#include <hip/hip_runtime.h>
#include <math.h>

// Problem constants (from setup_inputs)
#define BATCH 256
#define NQ 30
#define NK 100
#define HID 512
#define WORD 300
#define KIN 900          // WORD*3
#define KP 928           // KIN padded to multiple of 32
#define NANS 32000
#define NOUT 300
#define NOUTP 384        // NOUT padded (MFMA K for sim)
#define NTG 12           // NOUTP/32
#define NLAYERS 3
#define MQT (BATCH * NQ)   // 7680
#define MKT (BATCH * NK)   // 25600
#define SCALE 0.044194173824159216f  // 1/sqrt(512)
#define CLDST 136          // C-tile LDS row stride (u16)
#define SST 36             // S LDS row stride (floats)
#define PKL 40             // Pk LDS row stride (u16)
#define PQL 136            // Pq LDS row stride (u16)

typedef __attribute__((ext_vector_type(8))) short bf16x8;
typedef __attribute__((ext_vector_type(4))) float f32x4;
typedef unsigned short ushort_t;

__device__ __forceinline__ unsigned short f2bf(float f) {
  unsigned int u = __float_as_uint(f);
  u = (u + 0x7FFF + ((u >> 16) & 1)) >> 16;  // RNE
  return (unsigned short)u;
}
__device__ __forceinline__ float bf2f(unsigned short s) {
  return __uint_as_float(((unsigned int)s) << 16);
}

typedef const __attribute__((address_space(1))) unsigned int* gas_u32;
typedef __attribute__((address_space(3))) unsigned int* las_u32;
__device__ __forceinline__ void gld_lds16(const void* g, void* l) {
  __builtin_amdgcn_global_load_lds((gas_u32)g, (las_u32)l, 16, 0, 0);
}

// bijective XCD swizzle (m204)
__device__ __forceinline__ int xcd_swz_linear() {
  const int nwg = gridDim.x * gridDim.y;
  const int orig = blockIdx.y * gridDim.x + blockIdx.x;
  const int q = nwg >> 3, r = nwg & 7;
  const int xcd = orig & 7, idx = orig >> 3;
  return (xcd < r ? xcd * (q + 1) : r * (q + 1) + (xcd - r) * q) + idx;
}

// ---------------- reduction helpers ----------------
__device__ __forceinline__ float waveReduceSum(float v) {
#pragma unroll
  for (int o = 32; o > 0; o >>= 1) v += __shfl_xor(v, o);
  return v;
}
__device__ float blockReduceSum512(float v) {
  __shared__ float sm[8];
  int lane = threadIdx.x & 63, w = threadIdx.x >> 6;
  v = waveReduceSum(v);
  if (lane == 0) sm[w] = v;
  __syncthreads();
  float r = 0.f;
#pragma unroll
  for (int i = 0; i < 8; ++i) r += sm[i];
  __syncthreads();
  return r;
}

// ---------------- bf16 MFMA GEMM: 2-phase dbuf + LDS-staged bf16 epilogue --
template <int SWZB, int BIAS, int OUTF32, int OUTBF16, int ZC0, int RELU>
__global__ __launch_bounds__(256) void mfma_gemm2(
    const ushort_t* __restrict__ A1, const ushort_t* __restrict__ Bt1,
    const float* __restrict__ bias1, float* __restrict__ C1,
    ushort_t* __restrict__ Cb1, int M1b,
    const ushort_t* __restrict__ A2, const ushort_t* __restrict__ Bt2,
    const float* __restrict__ bias2, float* __restrict__ C2,
    ushort_t* __restrict__ Cb2,
    size_t zsA, size_t zsB, size_t zsC,
    int N, int K, int nbias) {
  __shared__ __align__(16) ushort_t smem[128 * CLDST];
  const int wg = xcd_swz_linear();
  const int bx = wg % gridDim.x, by = wg / gridDim.x;
  const int z = blockIdx.z;
  const bool sel = (by >= M1b);
  const ushort_t* A = (sel ? A2 : A1) + z * zsA;
  const ushort_t* Bt = (sel ? Bt2 : Bt1) + z * zsB;
  const float* bias = sel ? bias2 : bias1;
  float* C = (sel ? C2 : C1);
  ushort_t* Cb = (sel ? Cb2 : Cb1);
  if (C) C += z * zsC;
  if (Cb) Cb += z * zsC;
  const int row0 = (sel ? (by - M1b) : by) * 128;
  const int col0 = bx * 128;

  const int tid = threadIdx.x;
  const int lane = tid & 63, w = tid >> 6;
  const int wr = w >> 1, wc = w & 1;
  const int s_r = lane & 15, s_kq = lane >> 4;
  const int nt = K / 32;

  const size_t a_src0 = (size_t)(row0 + (w * 2 + 0) * 16 + s_r) * K + s_kq * 8;
  const size_t a_src1 = (size_t)(row0 + (w * 2 + 1) * 16 + s_r) * K + s_kq * 8;
  const size_t b_lin0 = (size_t)(col0 + (w * 2 + 0) * 16 + s_r) * K + s_kq * 8;
  const size_t b_lin1 = (size_t)(col0 + (w * 2 + 1) * 16 + s_r) * K + s_kq * 8;
  const size_t b_swz0 = ((size_t)(col0 >> 7) * nt) * 4096 + (w * 2 + 0) * 512 + lane * 8;
  const size_t b_swz1 = b_swz0 + 512;

  auto stageAB = [&](int t, int bsel) {
    const int k0 = t * 32;
    ushort_t* Ab = smem + bsel * 4096;
    ushort_t* Bb = smem + 8192 + bsel * 4096;
    gld_lds16(A + a_src0 + k0, Ab + (w * 2 + 0) * 512);
    gld_lds16(A + a_src1 + k0, Ab + (w * 2 + 1) * 512);
    if (SWZB) {
      gld_lds16(Bt + b_swz0 + (size_t)t * 4096, Bb + (w * 2 + 0) * 512);
      gld_lds16(Bt + b_swz1 + (size_t)t * 4096, Bb + (w * 2 + 1) * 512);
    } else {
      gld_lds16(Bt + b_lin0 + k0, Bb + (w * 2 + 0) * 512);
      gld_lds16(Bt + b_lin1 + k0, Bb + (w * 2 + 1) * 512);
    }
  };

  f32x4 acc[4][4];
#pragma unroll
  for (int i = 0; i < 4; ++i)
#pragma unroll
    for (int j = 0; j < 4; ++j) acc[i][j] = (f32x4){0.f, 0.f, 0.f, 0.f};

  stageAB(0, 0);
  __syncthreads();
  for (int t = 0; t < nt; ++t) {
    const int cur = t & 1;
    if (t + 1 < nt) stageAB(t + 1, cur ^ 1);
    const ushort_t* Ab = smem + cur * 4096;
    const ushort_t* Bb = smem + 8192 + cur * 4096;
    bf16x8 af[4], bfr[4];
#pragma unroll
    for (int mi = 0; mi < 4; ++mi)
      af[mi] = *(const bf16x8*)(Ab + (wr * 4 + mi) * 512 + lane * 8);
#pragma unroll
    for (int nj = 0; nj < 4; ++nj)
      bfr[nj] = *(const bf16x8*)(Bb + (wc * 4 + nj) * 512 + lane * 8);
#pragma unroll
    for (int mi = 0; mi < 4; ++mi)
#pragma unroll
      for (int nj = 0; nj < 4; ++nj)
        acc[mi][nj] = __builtin_amdgcn_mfma_f32_16x16x32_bf16(
            af[mi], bfr[nj], acc[mi][nj], 0, 0, 0);
    __syncthreads();
  }

  if (OUTBF16) {
#pragma unroll
    for (int nj = 0; nj < 4; ++nj) {
      const int nl = wc * 64 + nj * 16 + (lane & 15);
      const int n = col0 + nl;
      const float bb = BIAS ? ((n < nbias) ? bias[n] : 0.f) : 0.f;
#pragma unroll
      for (int mi = 0; mi < 4; ++mi) {
        f32x4 v = acc[mi][nj];
#pragma unroll
        for (int r = 0; r < 4; ++r) {
          const int ml = wr * 64 + mi * 16 + (lane >> 4) * 4 + r;
          float val = v[r] + bb;
          if (RELU) val = fmaxf(val, 0.f);
          if (ZC0 && n == 0) val = 0.f;
          smem[ml * CLDST + nl] = f2bf(val);
        }
      }
    }
    __syncthreads();
#pragma unroll
    for (int j = 0; j < 8; ++j) {
      const int e = j * 2048 + tid * 8;
      const int ml = e >> 7, nl = e & 127;
      uint4 v = *(const uint4*)(smem + ml * CLDST + nl);
      *(uint4*)(Cb + (size_t)(row0 + ml) * N + col0 + nl) = v;
    }
  }
  if (OUTF32) {
#pragma unroll
    for (int nj = 0; nj < 4; ++nj) {
      const int n = col0 + wc * 64 + nj * 16 + (lane & 15);
      const float bb = BIAS ? ((n < nbias) ? bias[n] : 0.f) : 0.f;
#pragma unroll
      for (int mi = 0; mi < 4; ++mi) {
        f32x4 v = acc[mi][nj];
#pragma unroll
        for (int r = 0; r < 4; ++r) {
          const int m = row0 + wr * 64 + mi * 16 + (lane >> 4) * 4 + r;
          float val = v[r] + bb;
          if (RELU) val = fmaxf(val, 0.f);
          if (ZC0 && n == 0) val = 0.f;
          C[(size_t)m * N + n] = val;
        }
      }
    }
  }
}

// ---------------- pre-cast kernels ----------------
__global__ __launch_bounds__(256) void gather_all_k(
    const int* __restrict__ qid, const int* __restrict__ kid,
    const float* __restrict__ emb, ushort_t* __restrict__ gq,
    ushort_t* __restrict__ gk) {
  int m = blockIdx.x;
  const int* ids;
  ushort_t* outp;
  if (m < MQT) {
    ids = qid + m * 3;
    outp = gq + (size_t)m * KP;
  } else {
    m -= MQT;
    ids = kid + m * 3;
    outp = gk + (size_t)m * KP;
  }
  const int t = threadIdx.x;
  if (t >= KP / 4) return;
  const int k = t * 4;
  ushort4 o = make_ushort4(0, 0, 0, 0);
  if (k < KIN) {
    const int node = (k >= 600) ? 2 : ((k >= 300) ? 1 : 0);
    const int off = k - node * 300;
    const int id = ids[node];
    float4 v = *(const float4*)(emb + (size_t)id * 300 + off);
    if (v.x != v.x) v.x = 0.f;
    if (v.y != v.y) v.y = 0.f;
    if (v.z != v.z) v.z = 0.f;
    if (v.w != v.w) v.w = 0.f;
    o = make_ushort4(f2bf(v.x), f2bf(v.y), f2bf(v.z), f2bf(v.w));
  }
  *(ushort4*)(outp + k) = o;
}

__global__ __launch_bounds__(256) void tcast4_k(
    const float* __restrict__ q2h_w, const float* __restrict__ k2h_w,
    const float* __restrict__ p1w, const float* __restrict__ p2w,
    ushort_t* __restrict__ q2h_wt, ushort_t* __restrict__ k2h_wt,
    ushort_t* __restrict__ p1wt, ushort_t* __restrict__ p2wt) {
  const int z = blockIdx.z;
  const float* src;
  ushort_t* dst;
  int R, Cc, Rp, Cp;
  if (z == 0)      { src = q2h_w; dst = q2h_wt; R = KIN;  Cc = HID;  Rp = KP;   Cp = HID; }
  else if (z == 1) { src = k2h_w; dst = k2h_wt; R = KIN;  Cc = HID;  Rp = KP;   Cp = HID; }
  else if (z == 2) { src = p1w; dst = p1wt; R = 1024; Cc = HID;  Rp = 1024; Cp = HID; }
  else             { src = p2w; dst = p2wt; R = HID;  Cc = NOUT; Rp = HID;  Cp = NOUTP; }
  const int r0 = blockIdx.y * 32, c0 = blockIdx.x * 32;
  if (r0 >= Rp || c0 >= Cp) return;
  __shared__ float t[32][33];
  const int tx = threadIdx.x & 31, ty = threadIdx.x >> 5;
#pragma unroll
  for (int i = 0; i < 4; ++i) {
    int r = r0 + ty + i * 8, c = c0 + tx;
    t[ty + i * 8][tx] = (r < R && c < Cc) ? src[(size_t)r * Cc + c] : 0.f;
  }
  __syncthreads();
#pragma unroll
  for (int i = 0; i < 4; ++i) {
    int c = c0 + ty + i * 8, r = r0 + tx;
    if (c < Cp && r < Rp) dst[(size_t)c * Rp + r] = f2bf(t[tx][ty + i * 8]);
  }
}

__global__ __launch_bounds__(256) void gcast_swz_k(
    const float* __restrict__ glove, ushort_t* __restrict__ gs) {
  const int ts = blockIdx.x, gp = blockIdx.y;
  ushort_t* dst = gs + ((size_t)gp * NTG + ts) * 4096;
  for (int g = threadIdx.x; g < 512; g += 256) {
    const int o = g * 8;
    const int chunk = o >> 9, kq = (o >> 7) & 3, rl = (o >> 3) & 15;
    const int row = gp * 128 + chunk * 16 + rl;
    const int kb = ts * 32 + kq * 8;
    ushort_t tmp[8];
    if (kb + 8 <= NOUT) {
      const float* s = glove + (size_t)row * NOUT + kb;
      float2 a0 = *(const float2*)(s + 0);
      float2 a1 = *(const float2*)(s + 2);
      float2 a2 = *(const float2*)(s + 4);
      float2 a3 = *(const float2*)(s + 6);
      tmp[0] = f2bf(a0.x); tmp[1] = f2bf(a0.y);
      tmp[2] = f2bf(a1.x); tmp[3] = f2bf(a1.y);
      tmp[4] = f2bf(a2.x); tmp[5] = f2bf(a2.y);
      tmp[6] = f2bf(a3.x); tmp[7] = f2bf(a3.y);
    } else {
#pragma unroll
      for (int j = 0; j < 8; ++j) {
        const int k = kb + j;
        tmp[j] = (k < NOUT) ? f2bf(glove[(size_t)row * NOUT + k]) : (ushort_t)0;
      }
    }
    *(ushort4*)(dst + o) = make_ushort4(tmp[0], tmp[1], tmp[2], tmp[3]);
    *(ushort4*)(dst + o + 4) = make_ushort4(tmp[4], tmp[5], tmp[6], tmp[7]);
  }
}

__global__ __launch_bounds__(128) void castrows_k(
    const float* __restrict__ Wk, const float* __restrict__ Wq,
    ushort_t* __restrict__ Wkr, ushort_t* __restrict__ Wqr) {
  const int idx = blockIdx.x;
  const int mat = idx >> 9, row = idx & 511;
  const float* src = (mat < 3 ? Wk + (size_t)mat * HID * HID
                              : Wq + (size_t)(mat - 3) * HID * HID) + (size_t)row * HID;
  ushort_t* dst = (mat < 3 ? Wkr + (size_t)mat * HID * HID
                           : Wqr + (size_t)(mat - 3) * HID * HID) + (size_t)row * HID;
  const int k = threadIdx.x * 4;
  float4 v = *(const float4*)(src + k);
  *(ushort4*)(dst + k) = make_ushort4(f2bf(v.x), f2bf(v.y), f2bf(v.z), f2bf(v.w));
}

// ---------------- S + dual softmax -> compact P operands -------------------
// grid (BATCH), 512 thr, LDS 16KB. Pk[b][128][32] (rows>=100 zeroed, cols
// 30/31 zeroed), Pq[b][32][128] (rows 30/31 zeroed, cols>=100 zeroed).
__global__ __launch_bounds__(512) void s_softmax_k(
    const ushort_t* __restrict__ Ktc, const ushort_t* __restrict__ Qp,
    ushort_t* __restrict__ Pkg, ushort_t* __restrict__ Pqg) {
  const int b = blockIdx.x;
  __shared__ __align__(16) float S_lds[112 * SST];
  const int tid = threadIdx.x;
  const int w = tid >> 6, lane = tid & 63;
  const ushort_t* ktb = Ktc + (size_t)b * NK * HID;
  if (w < 7) {
    const int r = lane & 15, kq = lane >> 4;
    const ushort_t* qpb = Qp + (size_t)b * NQ * HID;
    const int rowA = w * 16 + r;
    const int rowA_c = (rowA < NK) ? rowA : (NK - 1);
    const int qr1 = (16 + r) < NQ ? (16 + r) : NQ - 1;
    f32x4 a0 = {0.f, 0.f, 0.f, 0.f}, a1 = {0.f, 0.f, 0.f, 0.f};
    for (int k0 = 0; k0 < HID; k0 += 32) {
      bf16x8 af = *(const bf16x8*)(ktb + (size_t)rowA_c * HID + k0 + kq * 8);
      bf16x8 b0 = *(const bf16x8*)(qpb + (size_t)r * HID + k0 + kq * 8);
      bf16x8 b1 = *(const bf16x8*)(qpb + (size_t)qr1 * HID + k0 + kq * 8);
      a0 = __builtin_amdgcn_mfma_f32_16x16x32_bf16(af, b0, a0, 0, 0, 0);
      a1 = __builtin_amdgcn_mfma_f32_16x16x32_bf16(af, b1, a1, 0, 0, 0);
    }
    const int q0 = lane & 15, mb = (lane >> 4) * 4;
#pragma unroll
    for (int rr = 0; rr < 4; ++rr) {
      const int mA = w * 16 + mb + rr;
      if (mA < NK) {
        S_lds[mA * SST + q0] = a0[rr] * SCALE;
        if (q0 + 16 < NQ) S_lds[mA * SST + q0 + 16] = a1[rr] * SCALE;
      }
    }
  }
  __syncthreads();
  if (tid < NQ) {
    const int q = tid;
    float m = -1e30f;
    for (int kr = 0; kr < NK; ++kr) m = fmaxf(m, S_lds[kr * SST + q]);
    float s = 0.f;
    for (int kr = 0; kr < NK; ++kr) s += expf(S_lds[kr * SST + q] - m);
    float inv = 1.f / s;
    ushort_t* pq = Pqg + (size_t)b * 4096 + q * 128;
    for (int kr = 0; kr < NK; ++kr)
      pq[kr] = f2bf(expf(S_lds[kr * SST + q] - m) * inv);
    for (int kr = NK; kr < 128; ++kr) pq[kr] = 0;
  } else if (tid < 32) {
    ushort_t* pq = Pqg + (size_t)b * 4096 + tid * 128;
    for (int kr = 0; kr < 128; ++kr) pq[kr] = 0;
  } else if (tid < 32 + NK) {
    const int kr = tid - 32;
    float m = -1e30f;
#pragma unroll
    for (int q = 0; q < NQ; ++q) m = fmaxf(m, S_lds[kr * SST + q]);
    float s = 0.f;
    float e[NQ];
#pragma unroll
    for (int q = 0; q < NQ; ++q) {
      e[q] = expf(S_lds[kr * SST + q] - m);
      s += e[q];
    }
    float inv = 1.f / s;
    ushort_t* pk = Pkg + (size_t)b * 4096 + kr * 32;
#pragma unroll
    for (int q = 0; q < NQ; ++q) pk[q] = f2bf(e[q] * inv);
    pk[30] = 0;
    pk[31] = 0;
  } else if (tid < 32 + 128) {
    // zero Pk rows 100..127
    const int kr = tid - 32;
    ushort_t* pk = Pkg + (size_t)b * 4096 + kr * 32;
    for (int q = 0; q < 32; ++q) pk[q] = 0;
  }
}

// ---------------- PV: per-batch column chunk, both products via MFMA -------
// grid (4, BATCH), 512 thr, LDS ~52KB (3 blocks/CU).
// waves 0-3: att_k = Pk @ qt + kt (chunk cols); waves 4-7: att_q = Pq @ kt + qt
__global__ __launch_bounds__(512) void pv_k(
    const ushort_t* __restrict__ Pkg, const ushort_t* __restrict__ Pqg,
    const ushort_t* __restrict__ Ktc, const ushort_t* __restrict__ Qc,
    ushort_t* __restrict__ Kn, ushort_t* __restrict__ Qn) {
  const int b = blockIdx.y;
  const int c0 = blockIdx.x * 128;
  __shared__ __align__(16) ushort_t kts[NK * 128];     // 25.6 KB (stride 256B)
  __shared__ __align__(16) ushort_t qts[NQ * 128];     // 7.7 KB
  __shared__ __align__(16) ushort_t Pk_l[128 * PKL];   // 10.2 KB
  __shared__ __align__(16) ushort_t Pq_l[32 * PQL];    // 8.7 KB
  const int tid = threadIdx.x;
  const int w = tid >> 6, lane = tid & 63;
  const ushort_t* ktb = Ktc + (size_t)b * NK * HID;
  const ushort_t* qtb = Qc + (size_t)b * NQ * HID;

  // stage kt/qt chunk: dest stride exactly 256B -> wave-linear (m104-safe)
  for (int e = tid; e < NK * 16; e += 512)
    gld_lds16(ktb + (size_t)(e >> 4) * HID + c0 + (e & 15) * 8, kts + e * 8);
  for (int e = tid; e < NQ * 16; e += 512)
    gld_lds16(qtb + (size_t)(e >> 4) * HID + c0 + (e & 15) * 8, qts + e * 8);
  // reg-stage P into padded (conflict-free) LDS
  {
    uint4 v1 = *(const uint4*)(Pkg + (size_t)b * 4096 + tid * 8);
    *(uint4*)(Pk_l + (tid >> 2) * PKL + (tid & 3) * 8) = v1;
    uint4 v2 = *(const uint4*)(Pqg + (size_t)b * 4096 + tid * 8);
    *(uint4*)(Pq_l + (tid >> 4) * PQL + (tid & 15) * 8) = v2;
  }
  __syncthreads();

  const int cl = lane & 15, g8 = (lane >> 4) * 8;
  if (w < 4) {
    // att_k: wave owns 32 cols of the chunk
    bf16x8 bk[2];
#pragma unroll
    for (int nt = 0; nt < 2; ++nt) {
      const int coll = w * 32 + nt * 16 + cl;
      union { ushort_t u[8]; bf16x8 v; } pb;
#pragma unroll
      for (int j = 0; j < 8; ++j) {
        int q = g8 + j;
        q = (q < NQ) ? q : (NQ - 1);
        pb.u[j] = qts[q * 128 + coll];
      }
      bk[nt] = pb.v;
    }
    ushort_t* kout = Kn + (size_t)b * NK * HID;
#pragma unroll
    for (int mt = 0; mt < 7; ++mt) {
      bf16x8 af = *(const bf16x8*)(Pk_l + (mt * 16 + cl) * PKL + g8);
      f32x4 ac[2];
#pragma unroll
      for (int nt = 0; nt < 2; ++nt) {
        ac[nt] = (f32x4){0.f, 0.f, 0.f, 0.f};
        ac[nt] = __builtin_amdgcn_mfma_f32_16x16x32_bf16(af, bk[nt], ac[nt], 0, 0, 0);
      }
#pragma unroll
      for (int nt = 0; nt < 2; ++nt) {
        const int coll = w * 32 + nt * 16 + cl;
        const int col = c0 + coll;
#pragma unroll
        for (int r = 0; r < 4; ++r) {
          const int row = mt * 16 + (lane >> 4) * 4 + r;
          if (row < NK) {
            float v = ac[nt][r] + bf2f(kts[row * 128 + coll]);
            kout[(size_t)row * HID + col] = f2bf(v);
          }
        }
      }
    }
  } else {
    // att_q: wave owns 32 cols of the chunk
    const int w4 = w - 4;
    f32x4 aq[2][2];
#pragma unroll
    for (int mt = 0; mt < 2; ++mt)
#pragma unroll
      for (int nt = 0; nt < 2; ++nt) aq[mt][nt] = (f32x4){0.f, 0.f, 0.f, 0.f};
#pragma unroll
    for (int ks = 0; ks < 4; ++ks) {
      bf16x8 bq[2];
#pragma unroll
      for (int nt = 0; nt < 2; ++nt) {
        const int coll = w4 * 32 + nt * 16 + cl;
        union { ushort_t u[8]; bf16x8 v; } pb;
#pragma unroll
        for (int j = 0; j < 8; ++j) {
          int kr = ks * 32 + g8 + j;
          kr = (kr < NK) ? kr : (NK - 1);
          pb.u[j] = kts[kr * 128 + coll];
        }
        bq[nt] = pb.v;
      }
#pragma unroll
      for (int mt = 0; mt < 2; ++mt) {
        bf16x8 af = *(const bf16x8*)(Pq_l + (mt * 16 + cl) * PQL + ks * 32 + g8);
#pragma unroll
        for (int nt = 0; nt < 2; ++nt)
          aq[mt][nt] = __builtin_amdgcn_mfma_f32_16x16x32_bf16(af, bq[nt], aq[mt][nt], 0, 0, 0);
      }
    }
    ushort_t* qout = Qn + (size_t)b * NQ * HID;
#pragma unroll
    for (int mt = 0; mt < 2; ++mt)
#pragma unroll
      for (int nt = 0; nt < 2; ++nt) {
        const int coll = w4 * 32 + nt * 16 + cl;
        const int col = c0 + coll;
#pragma unroll
        for (int r = 0; r < 4; ++r) {
          const int row = mt * 16 + (lane >> 4) * 4 + r;
          if (row < NQ) {
            float v = aq[mt][nt][r] + bf2f(qts[row * 128 + coll]);
            qout[(size_t)row * HID + col] = f2bf(v);
          }
        }
      }
  }
}

// ---------------- fused boundary: parallel row-norms ----------------
__global__ __launch_bounds__(512) void finale_k(
    const ushort_t* __restrict__ Kb, const ushort_t* __restrict__ Qb,
    ushort_t* __restrict__ lastb, const float* __restrict__ curv) {
  const int b = blockIdx.x, tid = threadIdx.x;
  const int w = tid >> 6, lane = tid & 63;
  const float c = curv[NLAYERS];
  const float Kc = 1.f / c, sqrtK = sqrtf(Kc);
  __shared__ float fsc[NK + NQ];
  __shared__ float fst[NK + NQ];
  const ushort_t* xkp = Kb + (size_t)b * NK * HID;
  const ushort_t* xqp = Qb + (size_t)b * NQ * HID;

  for (int r = w; r < NK + NQ; r += 8) {
    const ushort_t* row =
        (r < NK) ? (xkp + (size_t)r * HID) : (xqp + (size_t)(r - NK) * HID);
    bf16x8 v = *(const bf16x8*)(row + lane * 8);
    float ss = 0.f;
#pragma unroll
    for (int j = 0; j < 8; ++j) {
      float t = bf2f((unsigned short)v[j]);
      ss = fmaf(t, t, ss);
    }
    ss = waveReduceSum(ss);
    if (lane == 0) {
      float n = fmaxf(sqrtf(ss), 1e-15f);
      float f = sqrtK * sinhf(n / sqrtK) / n;
      fsc[r] = f;
      fst[r] = sqrtf(fmaxf(Kc + f * f * ss, 1e-7f));
    }
  }
  __syncthreads();

  float mk, mq;
  if (tid == 0) {
    float sk = 0.f, sq2 = 0.f;
    for (int r = 0; r < NK; ++r) sk += fst[r];
    for (int r = 0; r < NQ; ++r) sq2 += fst[NK + r];
    mk = sk;
    mq = sq2;
  } else {
    float sk = 0.f, sq2 = 0.f;
    for (int r = 0; r < NK; ++r)
      sk = fmaf(fsc[r], bf2f(xkp[(size_t)r * HID + tid]), sk);
    for (int r = 0; r < NQ; ++r)
      sq2 = fmaf(fsc[NK + r], bf2f(xqp[(size_t)r * HID + tid]), sq2);
    mk = sk;
    mq = sq2;
  }
  mk *= (1.f / NK);
  mq *= (1.f / NQ);

  float sq = ((tid == 0) ? 0.f : mk * mk) + mq * mq;
  float ssall = blockReduceSum512(sq);
  __shared__ float x0sh;
  if (tid == 0) x0sh = mk;
  __syncthreads();
  const float x0 = x0sh;
  const float n = fmaxf(sqrtf(ssall), 1e-15f);
  const float theta = fmaxf(x0 / sqrtK, 1.f + 1e-7f);
  const float rr = sqrtK * acoshf(theta) / n;
  ushort_t* ob = lastb + (size_t)b * 1024;
  ob[tid] = (tid == 0) ? (ushort_t)0 : f2bf(rr * mk);
  ob[512 + tid] = f2bf(rr * mq);
}

// ---------------- tail: 2-pass online log-softmax ----------------
__global__ __launch_bounds__(512) void logsoftmax_k(float* __restrict__ x) {
  const int b = blockIdx.x, tid = threadIdx.x;
  float4* row = (float4*)(x + (size_t)b * NANS);
  float m = -3.4e38f, s = 0.f;
  for (int i = tid; i < NANS / 4; i += 512) {
    float4 v = row[i];
    float lm = fmaxf(fmaxf(v.x, v.y), fmaxf(v.z, v.w));
    float nm = fmaxf(m, lm);
    s = s * expf(m - nm) + expf(v.x - nm) + expf(v.y - nm) +
        expf(v.z - nm) + expf(v.w - nm);
    m = nm;
  }
#pragma unroll
  for (int o = 32; o > 0; o >>= 1) {
    float mo = __shfl_xor(m, o);
    float so = __shfl_xor(s, o);
    float nm = fmaxf(m, mo);
    s = s * expf(m - nm) + so * expf(mo - nm);
    m = nm;
  }
  __shared__ float smm[8], sms[8];
  const int w = tid >> 6, lane = tid & 63;
  if (lane == 0) { smm[w] = m; sms[w] = s; }
  __syncthreads();
  float gm = smm[0], gs = sms[0];
#pragma unroll
  for (int i = 1; i < 8; ++i) {
    float nm = fmaxf(gm, smm[i]);
    gs = gs * expf(gm - nm) + sms[i] * expf(smm[i] - nm);
    gm = nm;
  }
  const float lse = gm + logf(gs);
  for (int i = tid; i < NANS / 4; i += 512) {
    float4 v = row[i];
    v.x -= lse; v.y -= lse; v.z -= lse; v.w -= lse;
    row[i] = v;
  }
}

// ---------------- launch ----------------
extern "C" void kernel_launch(void* const* d_in, const int* in_sizes, int n_in,
                              void* d_out, int out_size, void* d_ws, size_t ws_size,
                              hipStream_t stream) {
  const int* qid = (const int*)d_in[0];
  const int* kid = (const int*)d_in[1];
  const float* emb = (const float*)d_in[2];
  const float* q2h_w = (const float*)d_in[3];
  const float* q2h_b = (const float*)d_in[4];
  const float* k2h_w = (const float*)d_in[5];
  const float* k2h_b = (const float*)d_in[6];
  const float* Wk = (const float*)d_in[7];
  const float* Wq = (const float*)d_in[8];
  const float* curv = (const float*)d_in[9];
  const float* p1w = (const float*)d_in[10];
  const float* p1b = (const float*)d_in[11];
  const float* p2w = (const float*)d_in[12];
  const float* p2b = (const float*)d_in[13];
  const float* glove = (const float*)d_in[14];
  float* out = (float*)d_out;

  // ---- workspace layout (all bf16) ----
  ushort_t* u = (ushort_t*)d_ws;
  ushort_t* Ks0 = u;
  ushort_t* Ks1 = Ks0 + (size_t)MKT * HID;
  ushort_t* Qs0 = Ks1 + (size_t)MKT * HID;
  ushort_t* Qs1 = Qs0 + (size_t)MQT * HID;
  ushort_t* Qps = Qs1 + (size_t)MQT * HID;
  ushort_t* gq = Qps + (size_t)MQT * HID;
  ushort_t* gk = gq + (size_t)MQT * KP;
  ushort_t* q2h_wt = gk + (size_t)MKT * KP;
  ushort_t* k2h_wt = q2h_wt + (size_t)HID * KP;
  ushort_t* Wkr = k2h_wt + (size_t)HID * KP;
  ushort_t* Wqr = Wkr + (size_t)NLAYERS * HID * HID;
  ushort_t* Mb = Wqr + (size_t)NLAYERS * HID * HID;
  ushort_t* p1wt = Mb + (size_t)NLAYERS * HID * HID;
  ushort_t* p2wt = p1wt + (size_t)HID * 1024;
  ushort_t* lastb = p2wt + (size_t)NOUTP * HID;
  ushort_t* h1b = lastb + (size_t)BATCH * 1024;
  ushort_t* o2b = h1b + (size_t)BATCH * HID;
  ushort_t* gsw = o2b + (size_t)BATCH * NOUTP;
  ushort_t* Pkg = gsw + (size_t)250 * NTG * 4096;   // [256][128][32]
  ushort_t* Pqg = Pkg + (size_t)BATCH * 4096;       // [256][32][128]

  // ---- pre-casts ----
  gather_all_k<<<MQT + MKT, 256, 0, stream>>>(qid, kid, emb, gq, gk);
  tcast4_k<<<dim3(16, 32, 4), 256, 0, stream>>>(
      q2h_w, k2h_w, p1w, p2w, q2h_wt, k2h_wt, p1wt, p2wt);
  castrows_k<<<6 * HID, 128, 0, stream>>>(Wk, Wq, Wkr, Wqr);
  gcast_swz_k<<<dim3(NTG, 250), 256, 0, stream>>>(glove, gsw);

  // ---- M_i = Wk_i @ Wq_i^T (bf16 out), batched over z ----
  mfma_gemm2<0, 0, 0, 1, 0, 0><<<dim3(HID / 128, HID / 128, NLAYERS), 256, 0, stream>>>(
      Wkr, Wqr, nullptr, nullptr, Mb, HID / 128,
      Wkr, Wqr, nullptr, nullptr, Mb,
      (size_t)HID * HID, (size_t)HID * HID, (size_t)HID * HID, HID, HID, HID);

  // ---- input projections (merged q+k), fused proj_tan0, bf16 out ----
  mfma_gemm2<0, 1, 0, 1, 1, 0><<<dim3(HID / 128, MQT / 128 + MKT / 128), 256, 0, stream>>>(
      gq, q2h_wt, q2h_b, nullptr, Qs0, MQT / 128,
      gk, k2h_wt, k2h_b, nullptr, Ks0, 0, 0, 0, HID, KP, HID);

  // ---- layers in tangent space ----
  ushort_t* Kc = Ks0;
  ushort_t* Kn = Ks1;
  ushort_t* Qc = Qs0;
  ushort_t* Qn = Qs1;
  for (int i = 0; i < NLAYERS; ++i) {
    // qp' = qt @ M_i^T
    mfma_gemm2<0, 0, 0, 1, 0, 0><<<dim3(HID / 128, MQT / 128), 256, 0, stream>>>(
        Qc, Mb + (size_t)i * HID * HID, nullptr, nullptr, Qps, MQT / 128,
        Qc, Mb + (size_t)i * HID * HID, nullptr, nullptr, Qps,
        0, 0, 0, HID, HID, HID);
    // S + softmaxes -> compact P
    s_softmax_k<<<BATCH, 512, 0, stream>>>(Kc, Qps, Pkg, Pqg);
    // PV (both products, MFMA, chunked for occupancy)
    pv_k<<<dim3(4, BATCH), 512, 0, stream>>>(Pkg, Pqg, Kc, Qc, Kn, Qn);
    ushort_t* t1 = Kc; Kc = Kn; Kn = t1;
    ushort_t* t2 = Qc; Qc = Qn; Qn = t2;
  }

  // ---- fused boundary (expproj + mean + logmap) -> lastb bf16 ----
  finale_k<<<BATCH, 512, 0, stream>>>(Kc, Qc, lastb, curv);

  // ---- head (all MFMA bf16) ----
  mfma_gemm2<0, 1, 0, 1, 0, 1><<<dim3(HID / 128, BATCH / 128), 256, 0, stream>>>(
      lastb, p1wt, p1b, nullptr, h1b, BATCH / 128,
      lastb, p1wt, p1b, nullptr, h1b, 0, 0, 0, HID, 1024, HID);
  mfma_gemm2<0, 1, 0, 1, 0, 0><<<dim3(NOUTP / 128, BATCH / 128), 256, 0, stream>>>(
      h1b, p2wt, p2b, nullptr, o2b, BATCH / 128,
      h1b, p2wt, p2b, nullptr, o2b, 0, 0, 0, NOUTP, HID, NOUT);
  // sim: B = swizzled glove bf16
  mfma_gemm2<1, 0, 1, 0, 0, 0><<<dim3(NANS / 128, BATCH / 128), 256, 0, stream>>>(
      o2b, gsw, nullptr, out, nullptr, BATCH / 128,
      o2b, gsw, nullptr, out, nullptr, 0, 0, 0, NANS, NOUTP, NANS);
  logsoftmax_k<<<BATCH, 512, 0, stream>>>(out);
}

// Round 21
// 395.908 us; speedup vs baseline: 1.4610x; 1.0046x over previous
//
#include <hip/hip_runtime.h>
#include <math.h>

// Problem constants (from setup_inputs)
#define BATCH 256
#define NQ 30
#define NK 100
#define HID 512
#define WORD 300
#define KIN 900          // WORD*3
#define KP 928           // KIN padded to multiple of 32
#define NANS 32000
#define NOUT 300
#define NOUTP 384        // NOUT padded (MFMA K for sim)
#define NTG 12           // NOUTP/32
#define NLAYERS 3
#define MQT (BATCH * NQ)   // 7680
#define MKT (BATCH * NK)   // 25600
#define SCALE 0.044194173824159216f  // 1/sqrt(512)
#define CLDST 136          // C-tile LDS row stride (u16)
#define FLDST 132          // f32 C-tile LDS row stride (floats)
#define SST 36             // S LDS row stride (floats)
#define PKL 40             // Pk LDS row stride (u16)
#define PQL 136            // Pq LDS row stride (u16)

typedef __attribute__((ext_vector_type(8))) short bf16x8;
typedef __attribute__((ext_vector_type(4))) float f32x4;
typedef unsigned short ushort_t;

__device__ __forceinline__ unsigned short f2bf(float f) {
  unsigned int u = __float_as_uint(f);
  u = (u + 0x7FFF + ((u >> 16) & 1)) >> 16;  // RNE
  return (unsigned short)u;
}
__device__ __forceinline__ float bf2f(unsigned short s) {
  return __uint_as_float(((unsigned int)s) << 16);
}

typedef const __attribute__((address_space(1))) unsigned int* gas_u32;
typedef __attribute__((address_space(3))) unsigned int* las_u32;
__device__ __forceinline__ void gld_lds16(const void* g, void* l) {
  __builtin_amdgcn_global_load_lds((gas_u32)g, (las_u32)l, 16, 0, 0);
}

// bijective XCD swizzle (m204)
__device__ __forceinline__ int xcd_swz_linear() {
  const int nwg = gridDim.x * gridDim.y;
  const int orig = blockIdx.y * gridDim.x + blockIdx.x;
  const int q = nwg >> 3, r = nwg & 7;
  const int xcd = orig & 7, idx = orig >> 3;
  return (xcd < r ? xcd * (q + 1) : r * (q + 1) + (xcd - r) * q) + idx;
}

// ---------------- reduction helpers ----------------
__device__ __forceinline__ float waveReduceSum(float v) {
#pragma unroll
  for (int o = 32; o > 0; o >>= 1) v += __shfl_xor(v, o);
  return v;
}
__device__ float blockReduceSum512(float v) {
  __shared__ float sm[8];
  int lane = threadIdx.x & 63, w = threadIdx.x >> 6;
  v = waveReduceSum(v);
  if (lane == 0) sm[w] = v;
  __syncthreads();
  float r = 0.f;
#pragma unroll
  for (int i = 0; i < 8; ++i) r += sm[i];
  __syncthreads();
  return r;
}

// ---------------- bf16 MFMA GEMM: 2-phase dbuf + LDS-staged epilogues ------
// OUTF32 now also stages through LDS (two 64-row halves) for full-line stores.
template <int SWZB, int BIAS, int OUTF32, int OUTBF16, int ZC0, int RELU>
__global__ __launch_bounds__(256) void mfma_gemm2(
    const ushort_t* __restrict__ A1, const ushort_t* __restrict__ Bt1,
    const float* __restrict__ bias1, float* __restrict__ C1,
    ushort_t* __restrict__ Cb1, int M1b,
    const ushort_t* __restrict__ A2, const ushort_t* __restrict__ Bt2,
    const float* __restrict__ bias2, float* __restrict__ C2,
    ushort_t* __restrict__ Cb2,
    size_t zsA, size_t zsB, size_t zsC,
    int N, int K, int nbias) {
  __shared__ __align__(16) ushort_t smem[128 * CLDST];
  const int wg = xcd_swz_linear();
  const int bx = wg % gridDim.x, by = wg / gridDim.x;
  const int z = blockIdx.z;
  const bool sel = (by >= M1b);
  const ushort_t* A = (sel ? A2 : A1) + z * zsA;
  const ushort_t* Bt = (sel ? Bt2 : Bt1) + z * zsB;
  const float* bias = sel ? bias2 : bias1;
  float* C = (sel ? C2 : C1);
  ushort_t* Cb = (sel ? Cb2 : Cb1);
  if (C) C += z * zsC;
  if (Cb) Cb += z * zsC;
  const int row0 = (sel ? (by - M1b) : by) * 128;
  const int col0 = bx * 128;

  const int tid = threadIdx.x;
  const int lane = tid & 63, w = tid >> 6;
  const int wr = w >> 1, wc = w & 1;
  const int s_r = lane & 15, s_kq = lane >> 4;
  const int nt = K / 32;

  const size_t a_src0 = (size_t)(row0 + (w * 2 + 0) * 16 + s_r) * K + s_kq * 8;
  const size_t a_src1 = (size_t)(row0 + (w * 2 + 1) * 16 + s_r) * K + s_kq * 8;
  const size_t b_lin0 = (size_t)(col0 + (w * 2 + 0) * 16 + s_r) * K + s_kq * 8;
  const size_t b_lin1 = (size_t)(col0 + (w * 2 + 1) * 16 + s_r) * K + s_kq * 8;
  const size_t b_swz0 = ((size_t)(col0 >> 7) * nt) * 4096 + (w * 2 + 0) * 512 + lane * 8;
  const size_t b_swz1 = b_swz0 + 512;

  auto stageAB = [&](int t, int bsel) {
    const int k0 = t * 32;
    ushort_t* Ab = smem + bsel * 4096;
    ushort_t* Bb = smem + 8192 + bsel * 4096;
    gld_lds16(A + a_src0 + k0, Ab + (w * 2 + 0) * 512);
    gld_lds16(A + a_src1 + k0, Ab + (w * 2 + 1) * 512);
    if (SWZB) {
      gld_lds16(Bt + b_swz0 + (size_t)t * 4096, Bb + (w * 2 + 0) * 512);
      gld_lds16(Bt + b_swz1 + (size_t)t * 4096, Bb + (w * 2 + 1) * 512);
    } else {
      gld_lds16(Bt + b_lin0 + k0, Bb + (w * 2 + 0) * 512);
      gld_lds16(Bt + b_lin1 + k0, Bb + (w * 2 + 1) * 512);
    }
  };

  f32x4 acc[4][4];
#pragma unroll
  for (int i = 0; i < 4; ++i)
#pragma unroll
    for (int j = 0; j < 4; ++j) acc[i][j] = (f32x4){0.f, 0.f, 0.f, 0.f};

  stageAB(0, 0);
  __syncthreads();
  for (int t = 0; t < nt; ++t) {
    const int cur = t & 1;
    if (t + 1 < nt) stageAB(t + 1, cur ^ 1);
    const ushort_t* Ab = smem + cur * 4096;
    const ushort_t* Bb = smem + 8192 + cur * 4096;
    bf16x8 af[4], bfr[4];
#pragma unroll
    for (int mi = 0; mi < 4; ++mi)
      af[mi] = *(const bf16x8*)(Ab + (wr * 4 + mi) * 512 + lane * 8);
#pragma unroll
    for (int nj = 0; nj < 4; ++nj)
      bfr[nj] = *(const bf16x8*)(Bb + (wc * 4 + nj) * 512 + lane * 8);
#pragma unroll
    for (int mi = 0; mi < 4; ++mi)
#pragma unroll
      for (int nj = 0; nj < 4; ++nj)
        acc[mi][nj] = __builtin_amdgcn_mfma_f32_16x16x32_bf16(
            af[mi], bfr[nj], acc[mi][nj], 0, 0, 0);
    __syncthreads();
  }

  if (OUTBF16) {
#pragma unroll
    for (int nj = 0; nj < 4; ++nj) {
      const int nl = wc * 64 + nj * 16 + (lane & 15);
      const int n = col0 + nl;
      const float bb = BIAS ? ((n < nbias) ? bias[n] : 0.f) : 0.f;
#pragma unroll
      for (int mi = 0; mi < 4; ++mi) {
        f32x4 v = acc[mi][nj];
#pragma unroll
        for (int r = 0; r < 4; ++r) {
          const int ml = wr * 64 + mi * 16 + (lane >> 4) * 4 + r;
          float val = v[r] + bb;
          if (RELU) val = fmaxf(val, 0.f);
          if (ZC0 && n == 0) val = 0.f;
          smem[ml * CLDST + nl] = f2bf(val);
        }
      }
    }
    __syncthreads();
#pragma unroll
    for (int j = 0; j < 8; ++j) {
      const int e = j * 2048 + tid * 8;
      const int ml = e >> 7, nl = e & 127;
      uint4 v = *(const uint4*)(smem + ml * CLDST + nl);
      *(uint4*)(Cb + (size_t)(row0 + ml) * N + col0 + nl) = v;
    }
  }
  if (OUTF32) {
    // two 64-row halves through LDS (f32) for full-line coalesced stores
    float* fs = (float*)smem;  // [64][FLDST]
#pragma unroll
    for (int h = 0; h < 2; ++h) {
      if (wr == h) {
#pragma unroll
        for (int nj = 0; nj < 4; ++nj) {
          const int nl = wc * 64 + nj * 16 + (lane & 15);
          const int n = col0 + nl;
          const float bb = BIAS ? ((n < nbias) ? bias[n] : 0.f) : 0.f;
#pragma unroll
          for (int mi = 0; mi < 4; ++mi) {
            f32x4 v = acc[mi][nj];
#pragma unroll
            for (int r = 0; r < 4; ++r) {
              const int ml = mi * 16 + (lane >> 4) * 4 + r;  // 0..63
              float val = v[r] + bb;
              if (RELU) val = fmaxf(val, 0.f);
              if (ZC0 && n == 0) val = 0.f;
              fs[ml * FLDST + nl] = val;
            }
          }
        }
      }
      __syncthreads();
#pragma unroll
      for (int j = 0; j < 8; ++j) {
        const int e = j * 256 + tid;       // float4 index, 0..2047
        const int ml = e >> 5, c4 = e & 31;
        float4 v = *(const float4*)(fs + ml * FLDST + c4 * 4);
        *(float4*)(C + (size_t)(row0 + h * 64 + ml) * N + col0 + c4 * 4) = v;
      }
      __syncthreads();
    }
  }
}

// ---------------- pre-cast kernels ----------------
__global__ __launch_bounds__(256) void gather_all_k(
    const int* __restrict__ qid, const int* __restrict__ kid,
    const float* __restrict__ emb, ushort_t* __restrict__ gq,
    ushort_t* __restrict__ gk) {
  int m = blockIdx.x;
  const int* ids;
  ushort_t* outp;
  if (m < MQT) {
    ids = qid + m * 3;
    outp = gq + (size_t)m * KP;
  } else {
    m -= MQT;
    ids = kid + m * 3;
    outp = gk + (size_t)m * KP;
  }
  const int t = threadIdx.x;
  if (t >= KP / 4) return;
  const int k = t * 4;
  ushort4 o = make_ushort4(0, 0, 0, 0);
  if (k < KIN) {
    const int node = (k >= 600) ? 2 : ((k >= 300) ? 1 : 0);
    const int off = k - node * 300;
    const int id = ids[node];
    float4 v = *(const float4*)(emb + (size_t)id * 300 + off);
    if (v.x != v.x) v.x = 0.f;
    if (v.y != v.y) v.y = 0.f;
    if (v.z != v.z) v.z = 0.f;
    if (v.w != v.w) v.w = 0.f;
    o = make_ushort4(f2bf(v.x), f2bf(v.y), f2bf(v.z), f2bf(v.w));
  }
  *(ushort4*)(outp + k) = o;
}

// transpose-cast + row-cast, 10 jobs:
// z=0 q2h^T, z=1 k2h^T, z=2 p1w^T, z=3 p2w^T, z=4..6 Wk[i] rowcast,
// z=7..9 Wq[i] rowcast
__global__ __launch_bounds__(256) void tcast10_k(
    const float* __restrict__ q2h_w, const float* __restrict__ k2h_w,
    const float* __restrict__ p1w, const float* __restrict__ p2w,
    const float* __restrict__ Wk, const float* __restrict__ Wq,
    ushort_t* __restrict__ q2h_wt, ushort_t* __restrict__ k2h_wt,
    ushort_t* __restrict__ p1wt, ushort_t* __restrict__ p2wt,
    ushort_t* __restrict__ Wkr, ushort_t* __restrict__ Wqr) {
  const int z = blockIdx.z;
  const int tx = threadIdx.x & 31, ty = threadIdx.x >> 5;
  if (z >= 4) {
    // row-cast 512x512
    const int i = (z - 4) % 3;
    const float* src = ((z < 7) ? Wk : Wq) + (size_t)i * HID * HID;
    ushort_t* dst = ((z < 7) ? Wkr : Wqr) + (size_t)i * HID * HID;
    const int r0 = blockIdx.y * 32, c0 = blockIdx.x * 32;
    if (r0 >= HID) return;
#pragma unroll
    for (int j = 0; j < 4; ++j) {
      const int r = r0 + ty + j * 8, c = c0 + tx;
      dst[(size_t)r * HID + c] = f2bf(src[(size_t)r * HID + c]);
    }
    return;
  }
  const float* src;
  ushort_t* dst;
  int R, Cc, Rp, Cp;
  if (z == 0)      { src = q2h_w; dst = q2h_wt; R = KIN;  Cc = HID;  Rp = KP;   Cp = HID; }
  else if (z == 1) { src = k2h_w; dst = k2h_wt; R = KIN;  Cc = HID;  Rp = KP;   Cp = HID; }
  else if (z == 2) { src = p1w; dst = p1wt; R = 1024; Cc = HID;  Rp = 1024; Cp = HID; }
  else             { src = p2w; dst = p2wt; R = HID;  Cc = NOUT; Rp = HID;  Cp = NOUTP; }
  const int r0 = blockIdx.y * 32, c0 = blockIdx.x * 32;
  if (r0 >= Rp || c0 >= Cp) return;
  __shared__ float t[32][33];
#pragma unroll
  for (int i = 0; i < 4; ++i) {
    int r = r0 + ty + i * 8, c = c0 + tx;
    t[ty + i * 8][tx] = (r < R && c < Cc) ? src[(size_t)r * Cc + c] : 0.f;
  }
  __syncthreads();
#pragma unroll
  for (int i = 0; i < 4; ++i) {
    int c = c0 + ty + i * 8, r = r0 + tx;
    if (c < Cp && r < Rp) dst[(size_t)c * Rp + r] = f2bf(t[tx][ty + i * 8]);
  }
}

__global__ __launch_bounds__(256) void gcast_swz_k(
    const float* __restrict__ glove, ushort_t* __restrict__ gs) {
  const int ts = blockIdx.x, gp = blockIdx.y;
  ushort_t* dst = gs + ((size_t)gp * NTG + ts) * 4096;
  for (int g = threadIdx.x; g < 512; g += 256) {
    const int o = g * 8;
    const int chunk = o >> 9, kq = (o >> 7) & 3, rl = (o >> 3) & 15;
    const int row = gp * 128 + chunk * 16 + rl;
    const int kb = ts * 32 + kq * 8;
    ushort_t tmp[8];
    if (kb + 8 <= NOUT) {
      const float* s = glove + (size_t)row * NOUT + kb;
      float2 a0 = *(const float2*)(s + 0);
      float2 a1 = *(const float2*)(s + 2);
      float2 a2 = *(const float2*)(s + 4);
      float2 a3 = *(const float2*)(s + 6);
      tmp[0] = f2bf(a0.x); tmp[1] = f2bf(a0.y);
      tmp[2] = f2bf(a1.x); tmp[3] = f2bf(a1.y);
      tmp[4] = f2bf(a2.x); tmp[5] = f2bf(a2.y);
      tmp[6] = f2bf(a3.x); tmp[7] = f2bf(a3.y);
    } else {
#pragma unroll
      for (int j = 0; j < 8; ++j) {
        const int k = kb + j;
        tmp[j] = (k < NOUT) ? f2bf(glove[(size_t)row * NOUT + k]) : (ushort_t)0;
      }
    }
    *(ushort4*)(dst + o) = make_ushort4(tmp[0], tmp[1], tmp[2], tmp[3]);
    *(ushort4*)(dst + o + 4) = make_ushort4(tmp[4], tmp[5], tmp[6], tmp[7]);
  }
}

// ---------------- S + dual softmax -> compact P operands -------------------
__global__ __launch_bounds__(512) void s_softmax_k(
    const ushort_t* __restrict__ Ktc, const ushort_t* __restrict__ Qp,
    ushort_t* __restrict__ Pkg, ushort_t* __restrict__ Pqg) {
  const int b = blockIdx.x;
  __shared__ __align__(16) float S_lds[112 * SST];
  const int tid = threadIdx.x;
  const int w = tid >> 6, lane = tid & 63;
  const ushort_t* ktb = Ktc + (size_t)b * NK * HID;
  if (w < 7) {
    const int r = lane & 15, kq = lane >> 4;
    const ushort_t* qpb = Qp + (size_t)b * NQ * HID;
    const int rowA = w * 16 + r;
    const int rowA_c = (rowA < NK) ? rowA : (NK - 1);
    const int qr1 = (16 + r) < NQ ? (16 + r) : NQ - 1;
    f32x4 a0 = {0.f, 0.f, 0.f, 0.f}, a1 = {0.f, 0.f, 0.f, 0.f};
    for (int k0 = 0; k0 < HID; k0 += 32) {
      bf16x8 af = *(const bf16x8*)(ktb + (size_t)rowA_c * HID + k0 + kq * 8);
      bf16x8 b0 = *(const bf16x8*)(qpb + (size_t)r * HID + k0 + kq * 8);
      bf16x8 b1 = *(const bf16x8*)(qpb + (size_t)qr1 * HID + k0 + kq * 8);
      a0 = __builtin_amdgcn_mfma_f32_16x16x32_bf16(af, b0, a0, 0, 0, 0);
      a1 = __builtin_amdgcn_mfma_f32_16x16x32_bf16(af, b1, a1, 0, 0, 0);
    }
    const int q0 = lane & 15, mb = (lane >> 4) * 4;
#pragma unroll
    for (int rr = 0; rr < 4; ++rr) {
      const int mA = w * 16 + mb + rr;
      if (mA < NK) {
        S_lds[mA * SST + q0] = a0[rr] * SCALE;
        if (q0 + 16 < NQ) S_lds[mA * SST + q0 + 16] = a1[rr] * SCALE;
      }
    }
  }
  __syncthreads();
  if (tid < NQ) {
    const int q = tid;
    float m = -1e30f;
    for (int kr = 0; kr < NK; ++kr) m = fmaxf(m, S_lds[kr * SST + q]);
    float s = 0.f;
    for (int kr = 0; kr < NK; ++kr) s += expf(S_lds[kr * SST + q] - m);
    float inv = 1.f / s;
    ushort_t* pq = Pqg + (size_t)b * 4096 + q * 128;
    for (int kr = 0; kr < NK; ++kr)
      pq[kr] = f2bf(expf(S_lds[kr * SST + q] - m) * inv);
    for (int kr = NK; kr < 128; ++kr) pq[kr] = 0;
  } else if (tid < 32) {
    ushort_t* pq = Pqg + (size_t)b * 4096 + tid * 128;
    for (int kr = 0; kr < 128; ++kr) pq[kr] = 0;
  } else if (tid < 32 + NK) {
    const int kr = tid - 32;
    float m = -1e30f;
#pragma unroll
    for (int q = 0; q < NQ; ++q) m = fmaxf(m, S_lds[kr * SST + q]);
    float s = 0.f;
    float e[NQ];
#pragma unroll
    for (int q = 0; q < NQ; ++q) {
      e[q] = expf(S_lds[kr * SST + q] - m);
      s += e[q];
    }
    float inv = 1.f / s;
    ushort_t* pk = Pkg + (size_t)b * 4096 + kr * 32;
#pragma unroll
    for (int q = 0; q < NQ; ++q) pk[q] = f2bf(e[q] * inv);
    pk[30] = 0;
    pk[31] = 0;
  } else if (tid < 32 + 128) {
    const int kr = tid - 32;
    ushort_t* pk = Pkg + (size_t)b * 4096 + kr * 32;
    for (int q = 0; q < 32; ++q) pk[q] = 0;
  }
}

// ---------------- PV: per-batch column chunk, both products via MFMA -------
__global__ __launch_bounds__(512) void pv_k(
    const ushort_t* __restrict__ Pkg, const ushort_t* __restrict__ Pqg,
    const ushort_t* __restrict__ Ktc, const ushort_t* __restrict__ Qc,
    ushort_t* __restrict__ Kn, ushort_t* __restrict__ Qn) {
  const int b = blockIdx.y;
  const int c0 = blockIdx.x * 128;
  __shared__ __align__(16) ushort_t kts[NK * 128];     // 25.6 KB
  __shared__ __align__(16) ushort_t qts[NQ * 128];     // 7.7 KB
  __shared__ __align__(16) ushort_t Pk_l[128 * PKL];   // 10.2 KB
  __shared__ __align__(16) ushort_t Pq_l[32 * PQL];    // 8.7 KB
  const int tid = threadIdx.x;
  const int w = tid >> 6, lane = tid & 63;
  const ushort_t* ktb = Ktc + (size_t)b * NK * HID;
  const ushort_t* qtb = Qc + (size_t)b * NQ * HID;

  for (int e = tid; e < NK * 16; e += 512)
    gld_lds16(ktb + (size_t)(e >> 4) * HID + c0 + (e & 15) * 8, kts + e * 8);
  for (int e = tid; e < NQ * 16; e += 512)
    gld_lds16(qtb + (size_t)(e >> 4) * HID + c0 + (e & 15) * 8, qts + e * 8);
  {
    uint4 v1 = *(const uint4*)(Pkg + (size_t)b * 4096 + tid * 8);
    *(uint4*)(Pk_l + (tid >> 2) * PKL + (tid & 3) * 8) = v1;
    uint4 v2 = *(const uint4*)(Pqg + (size_t)b * 4096 + tid * 8);
    *(uint4*)(Pq_l + (tid >> 4) * PQL + (tid & 15) * 8) = v2;
  }
  __syncthreads();

  const int cl = lane & 15, g8 = (lane >> 4) * 8;
  if (w < 4) {
    bf16x8 bk[2];
#pragma unroll
    for (int nt = 0; nt < 2; ++nt) {
      const int coll = w * 32 + nt * 16 + cl;
      union { ushort_t u[8]; bf16x8 v; } pb;
#pragma unroll
      for (int j = 0; j < 8; ++j) {
        int q = g8 + j;
        q = (q < NQ) ? q : (NQ - 1);
        pb.u[j] = qts[q * 128 + coll];
      }
      bk[nt] = pb.v;
    }
    ushort_t* kout = Kn + (size_t)b * NK * HID;
#pragma unroll
    for (int mt = 0; mt < 7; ++mt) {
      bf16x8 af = *(const bf16x8*)(Pk_l + (mt * 16 + cl) * PKL + g8);
      f32x4 ac[2];
#pragma unroll
      for (int nt = 0; nt < 2; ++nt) {
        ac[nt] = (f32x4){0.f, 0.f, 0.f, 0.f};
        ac[nt] = __builtin_amdgcn_mfma_f32_16x16x32_bf16(af, bk[nt], ac[nt], 0, 0, 0);
      }
#pragma unroll
      for (int nt = 0; nt < 2; ++nt) {
        const int coll = w * 32 + nt * 16 + cl;
        const int col = c0 + coll;
#pragma unroll
        for (int r = 0; r < 4; ++r) {
          const int row = mt * 16 + (lane >> 4) * 4 + r;
          if (row < NK) {
            float v = ac[nt][r] + bf2f(kts[row * 128 + coll]);
            kout[(size_t)row * HID + col] = f2bf(v);
          }
        }
      }
    }
  } else {
    const int w4 = w - 4;
    f32x4 aq[2][2];
#pragma unroll
    for (int mt = 0; mt < 2; ++mt)
#pragma unroll
      for (int nt = 0; nt < 2; ++nt) aq[mt][nt] = (f32x4){0.f, 0.f, 0.f, 0.f};
#pragma unroll
    for (int ks = 0; ks < 4; ++ks) {
      bf16x8 bq[2];
#pragma unroll
      for (int nt = 0; nt < 2; ++nt) {
        const int coll = w4 * 32 + nt * 16 + cl;
        union { ushort_t u[8]; bf16x8 v; } pb;
#pragma unroll
        for (int j = 0; j < 8; ++j) {
          int kr = ks * 32 + g8 + j;
          kr = (kr < NK) ? kr : (NK - 1);
          pb.u[j] = kts[kr * 128 + coll];
        }
        bq[nt] = pb.v;
      }
#pragma unroll
      for (int mt = 0; mt < 2; ++mt) {
        bf16x8 af = *(const bf16x8*)(Pq_l + (mt * 16 + cl) * PQL + ks * 32 + g8);
#pragma unroll
        for (int nt = 0; nt < 2; ++nt)
          aq[mt][nt] = __builtin_amdgcn_mfma_f32_16x16x32_bf16(af, bq[nt], aq[mt][nt], 0, 0, 0);
      }
    }
    ushort_t* qout = Qn + (size_t)b * NQ * HID;
#pragma unroll
    for (int mt = 0; mt < 2; ++mt)
#pragma unroll
      for (int nt = 0; nt < 2; ++nt) {
        const int coll = w4 * 32 + nt * 16 + cl;
        const int col = c0 + coll;
#pragma unroll
        for (int r = 0; r < 4; ++r) {
          const int row = mt * 16 + (lane >> 4) * 4 + r;
          if (row < NQ) {
            float v = aq[mt][nt][r] + bf2f(qts[row * 128 + coll]);
            qout[(size_t)row * HID + col] = f2bf(v);
          }
        }
      }
  }
}

// ---------------- fused boundary: parallel row-norms ----------------
__global__ __launch_bounds__(512) void finale_k(
    const ushort_t* __restrict__ Kb, const ushort_t* __restrict__ Qb,
    ushort_t* __restrict__ lastb, const float* __restrict__ curv) {
  const int b = blockIdx.x, tid = threadIdx.x;
  const int w = tid >> 6, lane = tid & 63;
  const float c = curv[NLAYERS];
  const float Kc = 1.f / c, sqrtK = sqrtf(Kc);
  __shared__ float fsc[NK + NQ];
  __shared__ float fst[NK + NQ];
  const ushort_t* xkp = Kb + (size_t)b * NK * HID;
  const ushort_t* xqp = Qb + (size_t)b * NQ * HID;

  for (int r = w; r < NK + NQ; r += 8) {
    const ushort_t* row =
        (r < NK) ? (xkp + (size_t)r * HID) : (xqp + (size_t)(r - NK) * HID);
    bf16x8 v = *(const bf16x8*)(row + lane * 8);
    float ss = 0.f;
#pragma unroll
    for (int j = 0; j < 8; ++j) {
      float t = bf2f((unsigned short)v[j]);
      ss = fmaf(t, t, ss);
    }
    ss = waveReduceSum(ss);
    if (lane == 0) {
      float n = fmaxf(sqrtf(ss), 1e-15f);
      float f = sqrtK * sinhf(n / sqrtK) / n;
      fsc[r] = f;
      fst[r] = sqrtf(fmaxf(Kc + f * f * ss, 1e-7f));
    }
  }
  __syncthreads();

  float mk, mq;
  if (tid == 0) {
    float sk = 0.f, sq2 = 0.f;
    for (int r = 0; r < NK; ++r) sk += fst[r];
    for (int r = 0; r < NQ; ++r) sq2 += fst[NK + r];
    mk = sk;
    mq = sq2;
  } else {
    float sk = 0.f, sq2 = 0.f;
    for (int r = 0; r < NK; ++r)
      sk = fmaf(fsc[r], bf2f(xkp[(size_t)r * HID + tid]), sk);
    for (int r = 0; r < NQ; ++r)
      sq2 = fmaf(fsc[NK + r], bf2f(xqp[(size_t)r * HID + tid]), sq2);
    mk = sk;
    mq = sq2;
  }
  mk *= (1.f / NK);
  mq *= (1.f / NQ);

  float sq = ((tid == 0) ? 0.f : mk * mk) + mq * mq;
  float ssall = blockReduceSum512(sq);
  __shared__ float x0sh;
  if (tid == 0) x0sh = mk;
  __syncthreads();
  const float x0 = x0sh;
  const float n = fmaxf(sqrtf(ssall), 1e-15f);
  const float theta = fmaxf(x0 / sqrtK, 1.f + 1e-7f);
  const float rr = sqrtK * acoshf(theta) / n;
  ushort_t* ob = lastb + (size_t)b * 1024;
  ob[tid] = (tid == 0) ? (ushort_t)0 : f2bf(rr * mk);
  ob[512 + tid] = f2bf(rr * mq);
}

// ---------------- tail: 2-pass online log-softmax ----------------
__global__ __launch_bounds__(512) void logsoftmax_k(float* __restrict__ x) {
  const int b = blockIdx.x, tid = threadIdx.x;
  float4* row = (float4*)(x + (size_t)b * NANS);
  float m = -3.4e38f, s = 0.f;
  for (int i = tid; i < NANS / 4; i += 512) {
    float4 v = row[i];
    float lm = fmaxf(fmaxf(v.x, v.y), fmaxf(v.z, v.w));
    float nm = fmaxf(m, lm);
    s = s * expf(m - nm) + expf(v.x - nm) + expf(v.y - nm) +
        expf(v.z - nm) + expf(v.w - nm);
    m = nm;
  }
#pragma unroll
  for (int o = 32; o > 0; o >>= 1) {
    float mo = __shfl_xor(m, o);
    float so = __shfl_xor(s, o);
    float nm = fmaxf(m, mo);
    s = s * expf(m - nm) + so * expf(mo - nm);
    m = nm;
  }
  __shared__ float smm[8], sms[8];
  const int w = tid >> 6, lane = tid & 63;
  if (lane == 0) { smm[w] = m; sms[w] = s; }
  __syncthreads();
  float gm = smm[0], gs = sms[0];
#pragma unroll
  for (int i = 1; i < 8; ++i) {
    float nm = fmaxf(gm, smm[i]);
    gs = gs * expf(gm - nm) + sms[i] * expf(smm[i] - nm);
    gm = nm;
  }
  const float lse = gm + logf(gs);
  for (int i = tid; i < NANS / 4; i += 512) {
    float4 v = row[i];
    v.x -= lse; v.y -= lse; v.z -= lse; v.w -= lse;
    row[i] = v;
  }
}

// ---------------- launch ----------------
extern "C" void kernel_launch(void* const* d_in, const int* in_sizes, int n_in,
                              void* d_out, int out_size, void* d_ws, size_t ws_size,
                              hipStream_t stream) {
  const int* qid = (const int*)d_in[0];
  const int* kid = (const int*)d_in[1];
  const float* emb = (const float*)d_in[2];
  const float* q2h_w = (const float*)d_in[3];
  const float* q2h_b = (const float*)d_in[4];
  const float* k2h_w = (const float*)d_in[5];
  const float* k2h_b = (const float*)d_in[6];
  const float* Wk = (const float*)d_in[7];
  const float* Wq = (const float*)d_in[8];
  const float* curv = (const float*)d_in[9];
  const float* p1w = (const float*)d_in[10];
  const float* p1b = (const float*)d_in[11];
  const float* p2w = (const float*)d_in[12];
  const float* p2b = (const float*)d_in[13];
  const float* glove = (const float*)d_in[14];
  float* out = (float*)d_out;

  // ---- workspace layout (all bf16) ----
  ushort_t* u = (ushort_t*)d_ws;
  ushort_t* Ks0 = u;
  ushort_t* Ks1 = Ks0 + (size_t)MKT * HID;
  ushort_t* Qs0 = Ks1 + (size_t)MKT * HID;
  ushort_t* Qs1 = Qs0 + (size_t)MQT * HID;
  ushort_t* Qps = Qs1 + (size_t)MQT * HID;
  ushort_t* gq = Qps + (size_t)MQT * HID;
  ushort_t* gk = gq + (size_t)MQT * KP;
  ushort_t* q2h_wt = gk + (size_t)MKT * KP;
  ushort_t* k2h_wt = q2h_wt + (size_t)HID * KP;
  ushort_t* Wkr = k2h_wt + (size_t)HID * KP;
  ushort_t* Wqr = Wkr + (size_t)NLAYERS * HID * HID;
  ushort_t* Mb = Wqr + (size_t)NLAYERS * HID * HID;
  ushort_t* p1wt = Mb + (size_t)NLAYERS * HID * HID;
  ushort_t* p2wt = p1wt + (size_t)HID * 1024;
  ushort_t* lastb = p2wt + (size_t)NOUTP * HID;
  ushort_t* h1b = lastb + (size_t)BATCH * 1024;
  ushort_t* o2b = h1b + (size_t)BATCH * HID;
  ushort_t* gsw = o2b + (size_t)BATCH * NOUTP;
  ushort_t* Pkg = gsw + (size_t)250 * NTG * 4096;   // [256][128][32]
  ushort_t* Pqg = Pkg + (size_t)BATCH * 4096;       // [256][32][128]

  // ---- pre-casts ----
  gather_all_k<<<MQT + MKT, 256, 0, stream>>>(qid, kid, emb, gq, gk);
  tcast10_k<<<dim3(16, 32, 10), 256, 0, stream>>>(
      q2h_w, k2h_w, p1w, p2w, Wk, Wq, q2h_wt, k2h_wt, p1wt, p2wt, Wkr, Wqr);
  gcast_swz_k<<<dim3(NTG, 250), 256, 0, stream>>>(glove, gsw);

  // ---- M_i = Wk_i @ Wq_i^T (bf16 out), batched over z ----
  mfma_gemm2<0, 0, 0, 1, 0, 0><<<dim3(HID / 128, HID / 128, NLAYERS), 256, 0, stream>>>(
      Wkr, Wqr, nullptr, nullptr, Mb, HID / 128,
      Wkr, Wqr, nullptr, nullptr, Mb,
      (size_t)HID * HID, (size_t)HID * HID, (size_t)HID * HID, HID, HID, HID);

  // ---- input projections (merged q+k), fused proj_tan0, bf16 out ----
  mfma_gemm2<0, 1, 0, 1, 1, 0><<<dim3(HID / 128, MQT / 128 + MKT / 128), 256, 0, stream>>>(
      gq, q2h_wt, q2h_b, nullptr, Qs0, MQT / 128,
      gk, k2h_wt, k2h_b, nullptr, Ks0, 0, 0, 0, HID, KP, HID);

  // ---- layers in tangent space ----
  ushort_t* Kc = Ks0;
  ushort_t* Kn = Ks1;
  ushort_t* Qc = Qs0;
  ushort_t* Qn = Qs1;
  for (int i = 0; i < NLAYERS; ++i) {
    mfma_gemm2<0, 0, 0, 1, 0, 0><<<dim3(HID / 128, MQT / 128), 256, 0, stream>>>(
        Qc, Mb + (size_t)i * HID * HID, nullptr, nullptr, Qps, MQT / 128,
        Qc, Mb + (size_t)i * HID * HID, nullptr, nullptr, Qps,
        0, 0, 0, HID, HID, HID);
    s_softmax_k<<<BATCH, 512, 0, stream>>>(Kc, Qps, Pkg, Pqg);
    pv_k<<<dim3(4, BATCH), 512, 0, stream>>>(Pkg, Pqg, Kc, Qc, Kn, Qn);
    ushort_t* t1 = Kc; Kc = Kn; Kn = t1;
    ushort_t* t2 = Qc; Qc = Qn; Qn = t2;
  }

  // ---- fused boundary (expproj + mean + logmap) -> lastb bf16 ----
  finale_k<<<BATCH, 512, 0, stream>>>(Kc, Qc, lastb, curv);

  // ---- head (all MFMA bf16) ----
  mfma_gemm2<0, 1, 0, 1, 0, 1><<<dim3(HID / 128, BATCH / 128), 256, 0, stream>>>(
      lastb, p1wt, p1b, nullptr, h1b, BATCH / 128,
      lastb, p1wt, p1b, nullptr, h1b, 0, 0, 0, HID, 1024, HID);
  mfma_gemm2<0, 1, 0, 1, 0, 0><<<dim3(NOUTP / 128, BATCH / 128), 256, 0, stream>>>(
      h1b, p2wt, p2b, nullptr, o2b, BATCH / 128,
      h1b, p2wt, p2b, nullptr, o2b, 0, 0, 0, NOUTP, HID, NOUT);
  // sim: B = swizzled glove bf16, f32 out via LDS-staged coalesced stores
  mfma_gemm2<1, 0, 1, 0, 0, 0><<<dim3(NANS / 128, BATCH / 128), 256, 0, stream>>>(
      o2b, gsw, nullptr, out, nullptr, BATCH / 128,
      o2b, gsw, nullptr, out, nullptr, 0, 0, 0, NANS, NOUTP, NANS);
  logsoftmax_k<<<BATCH, 512, 0, stream>>>(out);
}